// Round 3
// baseline (382.547 us; speedup 1.0000x reference)
//
#include <hip/hip_runtime.h>
#include <hip/hip_bf16.h>
#include <stdint.h>

typedef __bf16 bf16_t;
typedef __bf16 bf16x8 __attribute__((ext_vector_type(8)));
typedef float  f32x4  __attribute__((ext_vector_type(4)));

__device__ __forceinline__ void gload16(const void* gp, void* lp) {
  __builtin_amdgcn_global_load_lds(
      (const __attribute__((address_space(1))) void*)(uintptr_t)gp,
      (__attribute__((address_space(3))) void*)(uintptr_t)lp,
      16, 0, 0);
}

__device__ __forceinline__ f32x4 mfma16(bf16x8 a, bf16x8 b, f32x4 c) {
  return __builtin_amdgcn_mfma_f32_16x16x32_bf16(a, b, c, 0, 0, 0);
}

// ---------------- fp32 -> bf16 cast (memory-bound, vectorized) ----------------
__global__ __launch_bounds__(256) void cast_f32_to_bf16(const float* __restrict__ in,
                                                        bf16_t* __restrict__ out, int n8) {
  int i = blockIdx.x * 256 + threadIdx.x;
  int stride = gridDim.x * 256;
  for (; i < n8; i += stride) {
    const f32x4* p = (const f32x4*)in + (size_t)i * 2;
    f32x4 a = p[0], b = p[1];
    bf16x8 o;
    o[0] = (bf16_t)a[0]; o[1] = (bf16_t)a[1]; o[2] = (bf16_t)a[2]; o[3] = (bf16_t)a[3];
    o[4] = (bf16_t)b[0]; o[5] = (bf16_t)b[1]; o[6] = (bf16_t)b[2]; o[7] = (bf16_t)b[3];
    ((bf16x8*)out)[i] = o;
  }
}

// ---------------- bf16 GEMM, C[m][n] = sum_k A[m][k]*B[n][k]  (m97 structure) ----------------
template<bool OUT_BF16>
__global__ __launch_bounds__(256, 2) void gemm_bt(const bf16_t* __restrict__ A,
                                                  const bf16_t* __restrict__ B,
                                                  void* __restrict__ Cout,
                                                  int M, int N, int K) {
  __shared__ __align__(16) bf16_t As[128 * 32];
  __shared__ __align__(16) bf16_t Bs[128 * 32];
  const int t = threadIdx.x;
  const int wid = t >> 6;
  const int l = t & 63;
  const int l15 = l & 15, l4 = l >> 4;
  const int wr = wid >> 1, wc = wid & 1;
  const long m0 = (long)blockIdx.x * 128;
  const long n0 = (long)blockIdx.y * 128;
  f32x4 acc[4][4] = {};
  for (int k0 = 0; k0 < K; k0 += 32) {
    #pragma unroll
    for (int it = 0; it < 2; ++it) {
      int idx = it * 256 + t;
      int row = idx >> 2, ch = idx & 3;   // 4x16B chunks per 64B row
      gload16(A + (m0 + row) * K + k0 + ch * 8, As + (size_t)(it * 256 + wid * 64) * 8);
      gload16(B + (n0 + row) * K + k0 + ch * 8, Bs + (size_t)(it * 256 + wid * 64) * 8);
    }
    __syncthreads();
    bf16x8 af[4], bfr[4];
    #pragma unroll
    for (int mf = 0; mf < 4; ++mf)
      af[mf] = *(const bf16x8*)(As + (wr * 64 + mf * 16 + l15) * 32 + l4 * 8);
    #pragma unroll
    for (int nf = 0; nf < 4; ++nf)
      bfr[nf] = *(const bf16x8*)(Bs + (wc * 64 + nf * 16 + l15) * 32 + l4 * 8);
    #pragma unroll
    for (int mf = 0; mf < 4; ++mf)
      #pragma unroll
      for (int nf = 0; nf < 4; ++nf)
        acc[mf][nf] = mfma16(af[mf], bfr[nf], acc[mf][nf]);
    __syncthreads();
  }
  // C/D layout: col = lane&15, row = (lane>>4)*4 + i   (m89-verified)
  #pragma unroll
  for (int mf = 0; mf < 4; ++mf)
    #pragma unroll
    for (int nf = 0; nf < 4; ++nf)
      #pragma unroll
      for (int i = 0; i < 4; ++i) {
        long r = m0 + wr * 64 + mf * 16 + l4 * 4 + i;
        long c = n0 + wc * 64 + nf * 16 + l15;
        if (OUT_BF16) ((bf16_t*)Cout)[r * N + c] = (bf16_t)acc[mf][nf][i];
        else          ((float*)Cout)[r * N + c] = acc[mf][nf][i];
      }
}

// ---------------- RoPE (rot_dim=32) + q-scale, in-place on qkv[4096][6144] ----------------
__global__ __launch_bounds__(256) void rope_scale(bf16_t* __restrict__ qkv) {
  int t = blockIdx.x * 256 + threadIdx.x;    // [0, 4096*256)
  int m = t >> 8;
  int h = (t >> 4) & 15;
  int j = t & 15;
  int n = m & 2047;
  const float L2_10000_D16 = 0.8304820237218406f;  // log2(10000)/16
  float inv = exp2f(-(float)j * L2_10000_D16);     // 10000^(-j/16)
  float ang = (float)n * inv;
  float s, c;
  sincosf(ang, &s, &c);
  const float scale = 0.08838834764831845f;        // 128^-0.5
  bf16_t* qp = qkv + (long)m * 6144 + h * 128;
  float a = (float)qp[j], b = (float)qp[j + 16];
  qp[j]      = (bf16_t)((a * c - b * s) * scale);
  qp[j + 16] = (bf16_t)((b * c + a * s) * scale);
  #pragma unroll
  for (int u = 0; u < 6; ++u) {
    int d = 32 + j + u * 16;
    qp[d] = (bf16_t)((float)qp[d] * scale);
  }
  bf16_t* kp = qp + 2048;
  a = (float)kp[j]; b = (float)kp[j + 16];
  kp[j]      = (bf16_t)(a * c - b * s);
  kp[j + 16] = (bf16_t)(b * c + a * s);
}

// ---------------- causal flash attention (balanced + pipelined) ----------------
// 512 blocks linear; half 0 -> qt, half 1 -> 15-qt (co-resident pairs sum to 34 tiles).
// K: Ks[2] double-buffered, XOR-swizzled rows, staged via pre-swizzled global src.
// V: per-lane 16B loads -> regs (two named sets, 2x-unrolled loop) -> XOR-swizzled Vt[128][64].
// P: per-wave Ps[32][72] (144B row stride, 16B-aligned).
__global__ __launch_bounds__(256, 2) void attn_causal(const bf16_t* __restrict__ qkv,
                                                      bf16_t* __restrict__ ao) {
  const int lin = blockIdx.x;
  const int idx = lin & 255, hf = lin >> 8;
  const int qraw = idx & 15;
  const int qt = hf ? 15 - qraw : qraw;
  const int bh = (hf << 4) | (idx >> 4);
  const int b = bh >> 4, h = bh & 15;
  const int t = threadIdx.x;
  const int wid = t >> 6, l = t & 63;
  const int l15 = l & 15, l4 = l >> 4;
  __shared__ __align__(16) bf16_t Ks[2][64 * 128];
  __shared__ __align__(16) bf16_t Vt[128 * 64];
  __shared__ __align__(16) bf16_t Ps[4][32 * 72];
  const bf16_t* base = qkv + (long)b * 2048 * 6144 + h * 128;
  const int q0w = qt * 128 + wid * 32;
  // Q fragments in registers (A-layout: row=l&15, k=(l>>4)*8+j)
  bf16x8 qf[2][4];
  #pragma unroll
  for (int mb = 0; mb < 2; ++mb)
    #pragma unroll
    for (int ks = 0; ks < 4; ++ks)
      qf[mb][ks] = *(const bf16x8*)(base + (long)(q0w + mb * 16 + l15) * 6144 + ks * 32 + l4 * 8);
  f32x4 o[2][8] = {};
  float mrun[2][4], lrun[2][4];
  #pragma unroll
  for (int mb = 0; mb < 2; ++mb)
    #pragma unroll
    for (int i = 0; i < 4; ++i) { mrun[mb][i] = -3.0e38f; lrun[mb][i] = 0.f; }

  bf16_t* pbuf = Ps[wid];
  const int ntiles = 2 * qt + 2;   // always even, >= 2

  auto stageK = [&](int tile, bf16_t* dst) {
    #pragma unroll
    for (int it = 0; it < 4; ++it) {
      int s = it * 256 + t;                    // 16B-chunk id, 0..1023
      int krow = s >> 4, kc = s & 15;
      int ksc = kc ^ (krow & 7);               // pre-swizzled source column
      gload16(base + 2048 + (long)(tile * 64 + krow) * 6144 + ksc * 8,
              dst + (size_t)(it * 256 + wid * 64) * 8);
    }
  };
  auto stageV = [&](int tile, bf16x8* vr) {
    const bf16_t* vsr = base + 4096 + (long)(tile * 64 + l) * 6144;
    #pragma unroll
    for (int it = 0; it < 4; ++it)
      vr[it] = *(const bf16x8*)(vsr + (it * 4 + wid) * 8);
  };
  auto writeVt = [&](const bf16x8* vr) {
    #pragma unroll
    for (int it = 0; it < 4; ++it) {
      int c = it * 4 + wid;                    // d-chunk 0..15
      #pragma unroll
      for (int i = 0; i < 8; ++i) {
        int row = c * 8 + i;
        Vt[row * 64 + (((l >> 3) ^ (row & 7)) * 8) + (l & 7)] = vr[it][i];
      }
    }
  };
  auto compute = [&](int kv0, const bf16_t* ksb) {
    if (kv0 > q0w + 31) return;
    // S = Q K^T (D: row=q-local, col=kv-local)
    f32x4 sa[2][4] = {};
    #pragma unroll
    for (int ks = 0; ks < 4; ++ks) {
      #pragma unroll
      for (int nb = 0; nb < 4; ++nb) {
        int row = nb * 16 + l15;
        int cs = (ks * 4 + l4) ^ (row & 7);
        bf16x8 kf = *(const bf16x8*)(ksb + row * 128 + cs * 8);
        sa[0][nb] = mfma16(qf[0][ks], kf, sa[0][nb]);
        sa[1][nb] = mfma16(qf[1][ks], kf, sa[1][nb]);
      }
    }
    // online softmax (fp32); row stats via shfl_xor over the 16-lane col group
    #pragma unroll
    for (int mb = 0; mb < 2; ++mb) {
      #pragma unroll
      for (int i = 0; i < 4; ++i) {
        const int qrow = q0w + mb * 16 + l4 * 4 + i;
        float mt = -3.0e38f;
        #pragma unroll
        for (int nb = 0; nb < 4; ++nb) {
          int kvg = kv0 + nb * 16 + l15;
          float sv = sa[mb][nb][i];
          sv = (kvg <= qrow) ? sv : -3.0e38f;
          sa[mb][nb][i] = sv;
          mt = fmaxf(mt, sv);
        }
        mt = fmaxf(mt, __shfl_xor(mt, 1));
        mt = fmaxf(mt, __shfl_xor(mt, 2));
        mt = fmaxf(mt, __shfl_xor(mt, 4));
        mt = fmaxf(mt, __shfl_xor(mt, 8));
        const float mold = mrun[mb][i];
        const float mnew = fmaxf(mold, mt);
        const float corr = __expf(mold - mnew);
        float ps = 0.f;
        #pragma unroll
        for (int nb = 0; nb < 4; ++nb) {
          float p = __expf(sa[mb][nb][i] - mnew);
          sa[mb][nb][i] = p;
          ps += p;
        }
        ps += __shfl_xor(ps, 1);
        ps += __shfl_xor(ps, 2);
        ps += __shfl_xor(ps, 4);
        ps += __shfl_xor(ps, 8);
        mrun[mb][i] = mnew;
        lrun[mb][i] = lrun[mb][i] * corr + ps;
        #pragma unroll
        for (int nf = 0; nf < 8; ++nf) o[mb][nf][i] *= corr;
      }
    }
    // P -> per-wave LDS (bf16, XOR-swizzled 8-el chunks, row stride 72)
    #pragma unroll
    for (int mb = 0; mb < 2; ++mb)
      #pragma unroll
      for (int nb = 0; nb < 4; ++nb)
        #pragma unroll
        for (int i = 0; i < 4; ++i) {
          int prow = mb * 16 + l4 * 4 + i;
          int pcol = nb * 16 + l15;
          int cw = (pcol >> 3) ^ (prow & 7);
          pbuf[prow * 72 + cw * 8 + (pcol & 7)] = (bf16_t)sa[mb][nb][i];
        }
    // O += P V
    #pragma unroll
    for (int ks2 = 0; ks2 < 2; ++ks2) {
      bf16x8 pf0 = *(const bf16x8*)(pbuf + l15 * 72 + (((ks2 * 4 + l4) ^ (l15 & 7)) * 8));
      bf16x8 pf1 = *(const bf16x8*)(pbuf + (16 + l15) * 72 + (((ks2 * 4 + l4) ^ (l15 & 7)) * 8));
      #pragma unroll
      for (int nf = 0; nf < 8; ++nf) {
        int row = nf * 16 + l15;
        bf16x8 vf = *(const bf16x8*)(Vt + row * 64 + (((ks2 * 4 + l4) ^ (l15 & 7)) * 8));
        o[0][nf] = mfma16(pf0, vf, o[0][nf]);
        o[1][nf] = mfma16(pf1, vf, o[1][nf]);
      }
    }
  };

  bf16x8 vrA[4], vrB[4];
  stageV(0, vrA);
  stageK(0, Ks[0]);
  for (int tile = 0; tile < ntiles; tile += 2) {
    // ---- even tile: consume vrA/Ks[0]; prefetch tile+1 into vrB/Ks[1]
    writeVt(vrA);
    __syncthreads();
    stageV(tile + 1, vrB);          // always valid: ntiles even
    stageK(tile + 1, Ks[1]);
    compute(tile * 64, Ks[0]);
    __syncthreads();
    // ---- odd tile: consume vrB/Ks[1]; prefetch tile+2 into vrA/Ks[0]
    writeVt(vrB);
    __syncthreads();
    if (tile + 2 < ntiles) {
      stageV(tile + 2, vrA);
      stageK(tile + 2, Ks[0]);
    }
    compute((tile + 1) * 64, Ks[1]);
    __syncthreads();
  }
  // epilogue: O /= l, write bf16 to ao[b][n][h*128+d]
  bf16_t* aob = ao + (long)b * 2048 * 2048 + h * 128;
  #pragma unroll
  for (int mb = 0; mb < 2; ++mb)
    #pragma unroll
    for (int i = 0; i < 4; ++i) {
      long qrow = q0w + mb * 16 + l4 * 4 + i;
      float inv = 1.f / lrun[mb][i];
      #pragma unroll
      for (int nf = 0; nf < 8; ++nf)
        aob[qrow * 2048 + nf * 16 + l15] = (bf16_t)(o[mb][nf][i] * inv);
    }
}

// ---------------- launch ----------------
extern "C" void kernel_launch(void* const* d_in, const int* in_sizes, int n_in,
                              void* d_out, int out_size, void* d_ws, size_t ws_size,
                              hipStream_t stream) {
  const float* x     = (const float*)d_in[0];
  const float* w_qkv = (const float*)d_in[1];
  const float* w_out = (const float*)d_in[2];
  // d_in[3] (g) is unused by the reference.
  char* ws = (char*)d_ws;
  bf16_t* xb    = (bf16_t*)(ws + 0L);           // 16 MiB  (4096x2048)
  bf16_t* wqkvb = (bf16_t*)(ws + 16777216L);    // 24 MiB  (6144x2048)
  bf16_t* woutb = (bf16_t*)(ws + 41943040L);    //  8 MiB  (2048x2048)
  bf16_t* qkv   = (bf16_t*)(ws + 50331648L);    // 48 MiB  (4096x6144)
  bf16_t* ao    = (bf16_t*)(ws + 100663296L);   // 16 MiB  (4096x2048) -> end 112 MiB

  cast_f32_to_bf16<<<2048, 256, 0, stream>>>(x, xb, 1048576);
  cast_f32_to_bf16<<<2048, 256, 0, stream>>>(w_qkv, wqkvb, 1572864);
  cast_f32_to_bf16<<<1024, 256, 0, stream>>>(w_out, woutb, 524288);
  // qkv[m][f] = sum_c x[m][c] * w_qkv[f][c]
  gemm_bt<true ><<<dim3(32, 48), 256, 0, stream>>>(xb, wqkvb, (void*)qkv, 4096, 6144, 2048);
  rope_scale<<<4096, 256, 0, stream>>>(qkv);
  attn_causal<<<512, 256, 0, stream>>>(qkv, ao);
  // out[m][c] = sum_f ao[m][f] * w_out[c][f]
  gemm_bt<false><<<dim3(32, 16), 256, 0, stream>>>(ao, woutb, d_out, 4096, 2048, 2048);
}

// Round 4
// 289.939 us; speedup vs baseline: 1.3194x; 1.3194x over previous
//
#include <hip/hip_runtime.h>
#include <hip/hip_bf16.h>
#include <stdint.h>

typedef __bf16 bf16_t;
typedef __bf16 bf16x8 __attribute__((ext_vector_type(8)));
typedef float  f32x4  __attribute__((ext_vector_type(4)));

__device__ __forceinline__ void gload16(const void* gp, void* lp) {
  __builtin_amdgcn_global_load_lds(
      (const __attribute__((address_space(1))) void*)(uintptr_t)gp,
      (__attribute__((address_space(3))) void*)(uintptr_t)lp,
      16, 0, 0);
}

__device__ __forceinline__ f32x4 mfma16(bf16x8 a, bf16x8 b, f32x4 c) {
  return __builtin_amdgcn_mfma_f32_16x16x32_bf16(a, b, c, 0, 0, 0);
}

__device__ __forceinline__ uint32_t pack2(float a, float b) {
  uint16_t ba = __builtin_bit_cast(uint16_t, (bf16_t)a);
  uint16_t bb = __builtin_bit_cast(uint16_t, (bf16_t)b);
  return (uint32_t)ba | ((uint32_t)bb << 16);
}

// ---------------- fp32 -> bf16 cast (memory-bound, vectorized) ----------------
__global__ __launch_bounds__(256) void cast_f32_to_bf16(const float* __restrict__ in,
                                                        bf16_t* __restrict__ out, int n8) {
  int i = blockIdx.x * 256 + threadIdx.x;
  int stride = gridDim.x * 256;
  for (; i < n8; i += stride) {
    const f32x4* p = (const f32x4*)in + (size_t)i * 2;
    f32x4 a = p[0], b = p[1];
    bf16x8 o;
    o[0] = (bf16_t)a[0]; o[1] = (bf16_t)a[1]; o[2] = (bf16_t)a[2]; o[3] = (bf16_t)a[3];
    o[4] = (bf16_t)b[0]; o[5] = (bf16_t)b[1]; o[6] = (bf16_t)b[2]; o[7] = (bf16_t)b[3];
    ((bf16x8*)out)[i] = o;
  }
}

// ---------------- bf16 GEMM, C[m][n] = sum_k A[m][k]*B[n][k]  (m97 structure) ----------------
template<bool OUT_BF16>
__global__ __launch_bounds__(256, 2) void gemm_bt(const bf16_t* __restrict__ A,
                                                  const bf16_t* __restrict__ B,
                                                  void* __restrict__ Cout,
                                                  int M, int N, int K) {
  __shared__ __align__(16) bf16_t As[128 * 32];
  __shared__ __align__(16) bf16_t Bs[128 * 32];
  const int t = threadIdx.x;
  const int wid = t >> 6;
  const int l = t & 63;
  const int l15 = l & 15, l4 = l >> 4;
  const int wr = wid >> 1, wc = wid & 1;
  const long m0 = (long)blockIdx.x * 128;
  const long n0 = (long)blockIdx.y * 128;
  f32x4 acc[4][4] = {};
  for (int k0 = 0; k0 < K; k0 += 32) {
    #pragma unroll
    for (int it = 0; it < 2; ++it) {
      int idx = it * 256 + t;
      int row = idx >> 2, ch = idx & 3;   // 4x16B chunks per 64B row
      gload16(A + (m0 + row) * K + k0 + ch * 8, As + (size_t)(it * 256 + wid * 64) * 8);
      gload16(B + (n0 + row) * K + k0 + ch * 8, Bs + (size_t)(it * 256 + wid * 64) * 8);
    }
    __syncthreads();
    bf16x8 af[4], bfr[4];
    #pragma unroll
    for (int mf = 0; mf < 4; ++mf)
      af[mf] = *(const bf16x8*)(As + (wr * 64 + mf * 16 + l15) * 32 + l4 * 8);
    #pragma unroll
    for (int nf = 0; nf < 4; ++nf)
      bfr[nf] = *(const bf16x8*)(Bs + (wc * 64 + nf * 16 + l15) * 32 + l4 * 8);
    #pragma unroll
    for (int mf = 0; mf < 4; ++mf)
      #pragma unroll
      for (int nf = 0; nf < 4; ++nf)
        acc[mf][nf] = mfma16(af[mf], bfr[nf], acc[mf][nf]);
    __syncthreads();
  }
  // C/D layout: col = lane&15, row = (lane>>4)*4 + i   (m89-verified)
  #pragma unroll
  for (int mf = 0; mf < 4; ++mf)
    #pragma unroll
    for (int nf = 0; nf < 4; ++nf)
      #pragma unroll
      for (int i = 0; i < 4; ++i) {
        long r = m0 + wr * 64 + mf * 16 + l4 * 4 + i;
        long c = n0 + wc * 64 + nf * 16 + l15;
        if (OUT_BF16) ((bf16_t*)Cout)[r * N + c] = (bf16_t)acc[mf][nf][i];
        else          ((float*)Cout)[r * N + c] = acc[mf][nf][i];
      }
}

// ---------------- RoPE (rot_dim=32) + q-scale, in-place on qkv[4096][6144] ----------------
__global__ __launch_bounds__(256) void rope_scale(bf16_t* __restrict__ qkv) {
  int t = blockIdx.x * 256 + threadIdx.x;    // [0, 4096*256)
  int m = t >> 8;
  int h = (t >> 4) & 15;
  int j = t & 15;
  int n = m & 2047;
  const float L2_10000_D16 = 0.8304820237218406f;  // log2(10000)/16
  float inv = exp2f(-(float)j * L2_10000_D16);     // 10000^(-j/16)
  float ang = (float)n * inv;
  float s, c;
  sincosf(ang, &s, &c);
  const float scale = 0.08838834764831845f;        // 128^-0.5
  bf16_t* qp = qkv + (long)m * 6144 + h * 128;
  float a = (float)qp[j], b = (float)qp[j + 16];
  qp[j]      = (bf16_t)((a * c - b * s) * scale);
  qp[j + 16] = (bf16_t)((b * c + a * s) * scale);
  #pragma unroll
  for (int u = 0; u < 6; ++u) {
    int d = 32 + j + u * 16;
    qp[d] = (bf16_t)((float)qp[d] * scale);
  }
  bf16_t* kp = qp + 2048;
  a = (float)kp[j]; b = (float)kp[j + 16];
  kp[j]      = (bf16_t)(a * c - b * s);
  kp[j + 16] = (bf16_t)(b * c + a * s);
}

// ---------------- causal flash attention (swapped-QK^T, 8 waves, QBLK=16) ----------------
// Grid: 512 1D blocks, LPT order (qt descending, bh inner) for tail packing.
// Block: 512 thr = 8 waves; wave w owns q rows qt*128 + w*16 .. +15. KV tile = 64.
// S^T = mfma(K, Q): D col=l15=q, row=l4*4+i=kv -> in-lane softmax (2 shfl/reduce),
// defer-rescale (T13), P packed in-reg -> 8 b32 LDS writes -> A-frag b128 reads.
// K: Ks[2] dbuf via global_load_lds (pre-swizzled src); V: regs -> swizzled Vt after compute.
__global__ __launch_bounds__(512, 4) void attn_causal(const bf16_t* __restrict__ qkv,
                                                      bf16_t* __restrict__ ao) {
  const int id = blockIdx.x;
  const int qt = 15 - (id >> 5);             // LPT: longest first
  const int bh = id & 31;
  const int b = bh >> 4, h = bh & 15;
  const int t = threadIdx.x;
  const int wid = t >> 6, l = t & 63;
  const int l15 = l & 15, l4 = l >> 4;
  __shared__ __align__(16) bf16_t Ks0[64 * 128];
  __shared__ __align__(16) bf16_t Ks1[64 * 128];
  __shared__ __align__(16) bf16_t Vt[128 * 64];
  __shared__ __align__(16) bf16_t Pb[8][16 * 72];
  const bf16_t* base = qkv + (long)b * 2048 * 6144 + h * 128;
  const int q0w = qt * 128 + wid * 16;
  // Q fragments (B-operand: col=l15 <-> q, k = d = ks*32 + l4*8 + j)
  bf16x8 qf[4];
  #pragma unroll
  for (int ks = 0; ks < 4; ++ks)
    qf[ks] = *(const bf16x8*)(base + (long)(q0w + l15) * 6144 + ks * 32 + l4 * 8);
  f32x4 o[8] = {};
  float mrun = -1.0e30f, lrun = 0.f;
  bf16_t* pbuf = Pb[wid];
  bf16x8 vr0, vr1;
  const int ntiles = 2 * qt + 2;

  auto stageK = [&](int tile, bf16_t* dst) {
    const bf16_t* src = base + 2048 + (long)tile * 64 * 6144;
    #pragma unroll
    for (int it = 0; it < 2; ++it) {
      int s = it * 512 + t;                  // 16B chunk id, 0..1023
      int krow = s >> 4, kc = s & 15;
      int ksc = kc ^ (krow & 7);             // pre-swizzled source column
      gload16(src + (long)krow * 6144 + ksc * 8, dst + (size_t)s * 8);
    }
  };
  auto loadV = [&](int tile) {
    const bf16_t* vsr = base + 4096 + (long)(tile * 64 + l) * 6144;
    vr0 = *(const bf16x8*)(vsr + wid * 8);          // d chunk wid
    vr1 = *(const bf16x8*)(vsr + (8 + wid) * 8);    // d chunk 8+wid
  };
  auto writeVt = [&]() {
    #pragma unroll
    for (int it = 0; it < 2; ++it) {
      int c = it * 8 + wid;                  // d-chunk 0..15
      bf16x8 v = it ? vr1 : vr0;
      #pragma unroll
      for (int e = 0; e < 8; ++e) {
        int d = c * 8 + e;                   // d&7 == e
        Vt[d * 64 + (((l >> 3) ^ e) * 8) + (l & 7)] = v[e];
      }
    }
  };
  auto compute = [&](int kv0, const bf16_t* ksb) {
    if (kv0 > q0w + 15) return;
    f32x4 sa[4] = {};
    __builtin_amdgcn_s_setprio(1);
    #pragma unroll
    for (int ks = 0; ks < 4; ++ks) {
      #pragma unroll
      for (int nb = 0; nb < 4; ++nb) {
        int row = nb * 16 + l15;
        int cs = (ks * 4 + l4) ^ (row & 7);
        bf16x8 kf = *(const bf16x8*)(ksb + row * 128 + cs * 8);
        sa[nb] = mfma16(kf, qf[ks], sa[nb]);   // S^T: row=kv, col=q
      }
    }
    __builtin_amdgcn_s_setprio(0);
    // causal mask (only diagonal tiles)
    if (kv0 + 63 > q0w) {
      const int q = q0w + l15;
      #pragma unroll
      for (int nb = 0; nb < 4; ++nb)
        #pragma unroll
        for (int i = 0; i < 4; ++i)
          if (kv0 + nb * 16 + l4 * 4 + i > q) sa[nb][i] = -3.0e38f;
    }
    // in-lane max over 16 kv + 2 cross-group shuffles
    f32x4 mv;
    #pragma unroll
    for (int i = 0; i < 4; ++i)
      mv[i] = fmaxf(fmaxf(sa[0][i], sa[1][i]), fmaxf(sa[2][i], sa[3][i]));
    float pmax = fmaxf(fmaxf(mv[0], mv[1]), fmaxf(mv[2], mv[3]));
    pmax = fmaxf(pmax, __shfl_xor(pmax, 16));
    pmax = fmaxf(pmax, __shfl_xor(pmax, 32));
    // defer-rescale (T13)
    if (!__all(pmax - mrun <= 8.0f)) {
      float mnew = fmaxf(mrun, pmax);
      float corr = __expf(mrun - mnew);
      mrun = mnew;
      lrun *= corr;
      float cc[4];
      #pragma unroll
      for (int i = 0; i < 4; ++i) cc[i] = __shfl(corr, l4 * 4 + i);
      #pragma unroll
      for (int nf = 0; nf < 8; ++nf)
        #pragma unroll
        for (int i = 0; i < 4; ++i) o[nf][i] *= cc[i];
    }
    float ps = 0.f;
    #pragma unroll
    for (int nb = 0; nb < 4; ++nb)
      #pragma unroll
      for (int i = 0; i < 4; ++i) {
        float p = __expf(sa[nb][i] - mrun);
        sa[nb][i] = p;
        ps += p;
      }
    ps += __shfl_xor(ps, 16);
    ps += __shfl_xor(ps, 32);
    lrun += ps;
    // P pack -> per-wave LDS (row=q-local l15, XOR-swizzled 16B chunks, stride 72)
    #pragma unroll
    for (int nb = 0; nb < 4; ++nb) {
      int cw = (nb * 2 + (l4 >> 1)) ^ (l15 & 7);
      uint32_t* dst = (uint32_t*)(pbuf + l15 * 72 + cw * 8 + (l4 & 1) * 4);
      dst[0] = pack2(sa[nb][0], sa[nb][1]);
      dst[1] = pack2(sa[nb][2], sa[nb][3]);
    }
    // O += P V
    #pragma unroll
    for (int ks2 = 0; ks2 < 2; ++ks2) {
      bf16x8 pf = *(const bf16x8*)(pbuf + l15 * 72 + (((ks2 * 4 + l4) ^ (l15 & 7)) * 8));
      __builtin_amdgcn_s_setprio(1);
      #pragma unroll
      for (int nf = 0; nf < 8; ++nf) {
        int row = nf * 16 + l15;
        bf16x8 vf = *(const bf16x8*)(Vt + row * 64 + (((ks2 * 4 + l4) ^ (row & 7)) * 8));
        o[nf] = mfma16(pf, vf, o[nf]);
      }
      __builtin_amdgcn_s_setprio(0);
    }
  };

  stageK(0, Ks0);
  loadV(0);
  writeVt();
  __syncthreads();                 // drains Ks0 gloads too
  for (int tile = 0; tile < ntiles; ++tile) {
    bf16_t* cur = (tile & 1) ? Ks1 : Ks0;
    bf16_t* nxt = (tile & 1) ? Ks0 : Ks1;
    const bool pre = (tile + 1 < ntiles);
    if (pre) { stageK(tile + 1, nxt); loadV(tile + 1); }
    compute(tile * 64, cur);
    __syncthreads();               // all done reading Vt; drains K gloads
    if (pre) writeVt();
    __syncthreads();               // Vt(t+1) visible
  }
  // epilogue: O /= l, write bf16 to ao[b][n][h*128+d]
  float linv = 1.f / lrun;
  float li[4];
  #pragma unroll
  for (int i = 0; i < 4; ++i) li[i] = __shfl(linv, l4 * 4 + i);
  bf16_t* aob = ao + (long)b * 2048 * 2048 + h * 128;
  #pragma unroll
  for (int i = 0; i < 4; ++i) {
    long qrow = q0w + l4 * 4 + i;
    #pragma unroll
    for (int nf = 0; nf < 8; ++nf)
      aob[qrow * 2048 + nf * 16 + l15] = (bf16_t)(o[nf][i] * li[i]);
  }
}

// ---------------- launch ----------------
extern "C" void kernel_launch(void* const* d_in, const int* in_sizes, int n_in,
                              void* d_out, int out_size, void* d_ws, size_t ws_size,
                              hipStream_t stream) {
  const float* x     = (const float*)d_in[0];
  const float* w_qkv = (const float*)d_in[1];
  const float* w_out = (const float*)d_in[2];
  // d_in[3] (g) is unused by the reference.
  char* ws = (char*)d_ws;
  bf16_t* xb    = (bf16_t*)(ws + 0L);           // 16 MiB  (4096x2048)
  bf16_t* wqkvb = (bf16_t*)(ws + 16777216L);    // 24 MiB  (6144x2048)
  bf16_t* woutb = (bf16_t*)(ws + 41943040L);    //  8 MiB  (2048x2048)
  bf16_t* qkv   = (bf16_t*)(ws + 50331648L);    // 48 MiB  (4096x6144)
  bf16_t* ao    = (bf16_t*)(ws + 100663296L);   // 16 MiB  (4096x2048) -> end 112 MiB

  cast_f32_to_bf16<<<2048, 256, 0, stream>>>(x, xb, 1048576);
  cast_f32_to_bf16<<<2048, 256, 0, stream>>>(w_qkv, wqkvb, 1572864);
  cast_f32_to_bf16<<<1024, 256, 0, stream>>>(w_out, woutb, 524288);
  // qkv[m][f] = sum_c x[m][c] * w_qkv[f][c]
  gemm_bt<true ><<<dim3(32, 48), 256, 0, stream>>>(xb, wqkvb, (void*)qkv, 4096, 6144, 2048);
  rope_scale<<<4096, 256, 0, stream>>>(qkv);
  attn_causal<<<512, 512, 0, stream>>>(qkv, ao);
  // out[m][c] = sum_f ao[m][f] * w_out[c][f]
  gemm_bt<false><<<dim3(32, 16), 256, 0, stream>>>(ao, woutb, d_out, 4096, 2048, 2048);
}

// Round 5
// 285.509 us; speedup vs baseline: 1.3399x; 1.0155x over previous
//
#include <hip/hip_runtime.h>
#include <hip/hip_bf16.h>
#include <stdint.h>

typedef __bf16 bf16_t;
typedef __bf16 bf16x8 __attribute__((ext_vector_type(8)));
typedef float  f32x4  __attribute__((ext_vector_type(4)));

__device__ __forceinline__ void gload16(const void* gp, void* lp) {
  __builtin_amdgcn_global_load_lds(
      (const __attribute__((address_space(1))) void*)(uintptr_t)gp,
      (__attribute__((address_space(3))) void*)(uintptr_t)lp,
      16, 0, 0);
}

__device__ __forceinline__ f32x4 mfma16(bf16x8 a, bf16x8 b, f32x4 c) {
  return __builtin_amdgcn_mfma_f32_16x16x32_bf16(a, b, c, 0, 0, 0);
}

__device__ __forceinline__ uint32_t pack2(float a, float b) {
  uint16_t ba = __builtin_bit_cast(uint16_t, (bf16_t)a);
  uint16_t bb = __builtin_bit_cast(uint16_t, (bf16_t)b);
  return (uint32_t)ba | ((uint32_t)bb << 16);
}

// ---------------- fp32 -> bf16 cast (memory-bound, vectorized) ----------------
__global__ __launch_bounds__(256) void cast_f32_to_bf16(const float* __restrict__ in,
                                                        bf16_t* __restrict__ out, int n8) {
  int i = blockIdx.x * 256 + threadIdx.x;
  int stride = gridDim.x * 256;
  for (; i < n8; i += stride) {
    const f32x4* p = (const f32x4*)in + (size_t)i * 2;
    f32x4 a = p[0], b = p[1];
    bf16x8 o;
    o[0] = (bf16_t)a[0]; o[1] = (bf16_t)a[1]; o[2] = (bf16_t)a[2]; o[3] = (bf16_t)a[3];
    o[4] = (bf16_t)b[0]; o[5] = (bf16_t)b[1]; o[6] = (bf16_t)b[2]; o[7] = (bf16_t)b[3];
    ((bf16x8*)out)[i] = o;
  }
}

// ======== 8-phase 256x256 GEMM (m201 template), C[m][n] = sum_k A[m][k]*B[n][k] ========
// 512 thr = 8 waves (2M x 4N); per-wave C = 128x64. BK=64, 2 K-tiles double-buffered
// (128 KiB LDS). Per phase: ds_read subtile + stage one half-tile (2x gload_lds) +
// barrier + lgkmcnt(0) + 16 MFMA. Counted vmcnt(4) only at the tile boundary.
// LDS swizzle: 16B-chunk ^= (row&7), applied on gload source AND ds_read (rule #21).
__global__ __launch_bounds__(512, 2) void gemm8p_bt(const bf16_t* __restrict__ A,
                                                    const bf16_t* __restrict__ B,
                                                    bf16_t* __restrict__ C,
                                                    int M, int N, int K) {
  __shared__ __align__(16) bf16_t As[2][256 * 64];
  __shared__ __align__(16) bf16_t Bs[2][256 * 64];
  const int t = threadIdx.x;
  const int wid = t >> 6, l = t & 63;
  const int l15 = l & 15, l4 = l >> 4;
  const int wm = wid >> 2, wn = wid & 3;
  const long m0 = (long)blockIdx.x * 256;
  const long n0 = (long)blockIdx.y * 256;
  const int KT = K >> 6;   // 64-wide K tiles

  // stage one half-tile (128 rows x 64 cols): dst LDS linear, src column pre-swizzled
  auto stage = [&](const bf16_t* __restrict__ G, bf16_t* __restrict__ LB,
                   long grow0, int kt) {
    #pragma unroll
    for (int it = 0; it < 2; ++it) {
      int s = it * 512 + t;          // 16B chunk id 0..1023
      int r = s >> 3, c = s & 7;
      gload16(G + (grow0 + r) * (long)K + kt * 64 + ((c ^ (r & 7)) << 3),
              LB + r * 64 + c * 8);
    }
  };
  auto ldfrag = [&](const bf16_t* buf, int rloc, int kk) -> bf16x8 {
    return *(const bf16x8*)(buf + rloc * 64 + ((((kk << 2) + l4) ^ (rloc & 7)) << 3));
  };

  f32x4 acc[8][4] = {};

  // prologue: B0.lo, B0.hi, A0.lo, A0.hi, B1.lo, B1.hi ; allow newest 2 halves in flight
  stage(B, &Bs[0][0],        n0,       0);
  stage(B, &Bs[0][128 * 64], n0 + 128, 0);
  stage(A, &As[0][0],        m0,       0);
  stage(A, &As[0][128 * 64], m0 + 128, 0);
  stage(B, &Bs[1][0],        n0,       1);
  stage(B, &Bs[1][128 * 64], n0 + 128, 1);
  asm volatile("s_waitcnt vmcnt(4)" ::: "memory");
  asm volatile("s_barrier" ::: "memory");

  for (int kt = 0; kt < KT; ++kt) {
    const bf16_t* Ab = &As[kt & 1][0];
    const bf16_t* Bb = &Bs[kt & 1][0];
    bf16_t* Anx = &As[(kt + 1) & 1][0];   // A(kt+1): opposite buffer, free since kt-1 end
    bf16_t* Bnx = &Bs[kt & 1][0];         // B(kt+2): same parity; B(kt) consumed at P1
    const bool stA = (kt + 1 < KT), stB = (kt + 2 < KT);

    // ---- P1: B-frags (8) + A mr0,1 (4); stage A(kt+1).lo
    bf16x8 bfr[4][2];
    #pragma unroll
    for (int nr = 0; nr < 4; ++nr)
      #pragma unroll
      for (int kk = 0; kk < 2; ++kk)
        bfr[nr][kk] = ldfrag(Bb, wn * 64 + nr * 16 + l15, kk);
    {
      bf16x8 a00 = ldfrag(Ab, wm * 128 + 0 * 16 + l15, 0);
      bf16x8 a01 = ldfrag(Ab, wm * 128 + 0 * 16 + l15, 1);
      bf16x8 a10 = ldfrag(Ab, wm * 128 + 1 * 16 + l15, 0);
      bf16x8 a11 = ldfrag(Ab, wm * 128 + 1 * 16 + l15, 1);
      if (stA) stage(A, Anx, m0, kt + 1);
      asm volatile("s_barrier" ::: "memory");
      asm volatile("s_waitcnt lgkmcnt(0)" ::: "memory");
      __builtin_amdgcn_sched_barrier(0);
      __builtin_amdgcn_s_setprio(1);
      #pragma unroll
      for (int nr = 0; nr < 4; ++nr) {
        acc[0][nr] = mfma16(a00, bfr[nr][0], acc[0][nr]);
        acc[0][nr] = mfma16(a01, bfr[nr][1], acc[0][nr]);
        acc[1][nr] = mfma16(a10, bfr[nr][0], acc[1][nr]);
        acc[1][nr] = mfma16(a11, bfr[nr][1], acc[1][nr]);
      }
      __builtin_amdgcn_s_setprio(0);
      asm volatile("s_barrier" ::: "memory");
    }
    // ---- P2: A mr2,3; stage A(kt+1).hi
    {
      bf16x8 a00 = ldfrag(Ab, wm * 128 + 2 * 16 + l15, 0);
      bf16x8 a01 = ldfrag(Ab, wm * 128 + 2 * 16 + l15, 1);
      bf16x8 a10 = ldfrag(Ab, wm * 128 + 3 * 16 + l15, 0);
      bf16x8 a11 = ldfrag(Ab, wm * 128 + 3 * 16 + l15, 1);
      if (stA) stage(A, Anx + 128 * 64, m0 + 128, kt + 1);
      asm volatile("s_barrier" ::: "memory");
      asm volatile("s_waitcnt lgkmcnt(0)" ::: "memory");
      __builtin_amdgcn_sched_barrier(0);
      __builtin_amdgcn_s_setprio(1);
      #pragma unroll
      for (int nr = 0; nr < 4; ++nr) {
        acc[2][nr] = mfma16(a00, bfr[nr][0], acc[2][nr]);
        acc[2][nr] = mfma16(a01, bfr[nr][1], acc[2][nr]);
        acc[3][nr] = mfma16(a10, bfr[nr][0], acc[3][nr]);
        acc[3][nr] = mfma16(a11, bfr[nr][1], acc[3][nr]);
      }
      __builtin_amdgcn_s_setprio(0);
      asm volatile("s_barrier" ::: "memory");
    }
    // ---- P3: A mr4,5; stage B(kt+2).lo
    {
      bf16x8 a00 = ldfrag(Ab, wm * 128 + 4 * 16 + l15, 0);
      bf16x8 a01 = ldfrag(Ab, wm * 128 + 4 * 16 + l15, 1);
      bf16x8 a10 = ldfrag(Ab, wm * 128 + 5 * 16 + l15, 0);
      bf16x8 a11 = ldfrag(Ab, wm * 128 + 5 * 16 + l15, 1);
      if (stB) stage(B, Bnx, n0, kt + 2);
      asm volatile("s_barrier" ::: "memory");
      asm volatile("s_waitcnt lgkmcnt(0)" ::: "memory");
      __builtin_amdgcn_sched_barrier(0);
      __builtin_amdgcn_s_setprio(1);
      #pragma unroll
      for (int nr = 0; nr < 4; ++nr) {
        acc[4][nr] = mfma16(a00, bfr[nr][0], acc[4][nr]);
        acc[4][nr] = mfma16(a01, bfr[nr][1], acc[4][nr]);
        acc[5][nr] = mfma16(a10, bfr[nr][0], acc[5][nr]);
        acc[5][nr] = mfma16(a11, bfr[nr][1], acc[5][nr]);
      }
      __builtin_amdgcn_s_setprio(0);
      asm volatile("s_barrier" ::: "memory");
    }
    // ---- P4: A mr6,7; stage B(kt+2).hi; counted vmcnt at tile boundary
    {
      bf16x8 a00 = ldfrag(Ab, wm * 128 + 6 * 16 + l15, 0);
      bf16x8 a01 = ldfrag(Ab, wm * 128 + 6 * 16 + l15, 1);
      bf16x8 a10 = ldfrag(Ab, wm * 128 + 7 * 16 + l15, 0);
      bf16x8 a11 = ldfrag(Ab, wm * 128 + 7 * 16 + l15, 1);
      if (stB) stage(B, Bnx + 128 * 64, n0 + 128, kt + 2);
      asm volatile("s_barrier" ::: "memory");
      asm volatile("s_waitcnt lgkmcnt(0)" ::: "memory");
      __builtin_amdgcn_sched_barrier(0);
      __builtin_amdgcn_s_setprio(1);
      #pragma unroll
      for (int nr = 0; nr < 4; ++nr) {
        acc[6][nr] = mfma16(a00, bfr[nr][0], acc[6][nr]);
        acc[6][nr] = mfma16(a01, bfr[nr][1], acc[6][nr]);
        acc[7][nr] = mfma16(a10, bfr[nr][0], acc[7][nr]);
        acc[7][nr] = mfma16(a11, bfr[nr][1], acc[7][nr]);
      }
      __builtin_amdgcn_s_setprio(0);
      if (stB) asm volatile("s_waitcnt vmcnt(4)" ::: "memory");  // tile kt+1 landed; B(kt+2) may fly
      else     asm volatile("s_waitcnt vmcnt(0)" ::: "memory");  // tail: drain
      asm volatile("s_barrier" ::: "memory");
    }
  }

  // epilogue: C/D layout col=l15, row=l4*4+i (m89-verified)
  #pragma unroll
  for (int mr = 0; mr < 8; ++mr)
    #pragma unroll
    for (int nr = 0; nr < 4; ++nr)
      #pragma unroll
      for (int i = 0; i < 4; ++i) {
        long r = m0 + wm * 128 + mr * 16 + l4 * 4 + i;
        long c = n0 + wn * 64 + nr * 16 + l15;
        C[r * N + c] = (bf16_t)acc[mr][nr][i];
      }
}

// ---------------- bf16 GEMM, C[m][n] = sum_k A[m][k]*B[n][k]  (m97 structure) ----------------
template<bool OUT_BF16>
__global__ __launch_bounds__(256, 2) void gemm_bt(const bf16_t* __restrict__ A,
                                                  const bf16_t* __restrict__ B,
                                                  void* __restrict__ Cout,
                                                  int M, int N, int K) {
  __shared__ __align__(16) bf16_t As[128 * 32];
  __shared__ __align__(16) bf16_t Bs[128 * 32];
  const int t = threadIdx.x;
  const int wid = t >> 6;
  const int l = t & 63;
  const int l15 = l & 15, l4 = l >> 4;
  const int wr = wid >> 1, wc = wid & 1;
  const long m0 = (long)blockIdx.x * 128;
  const long n0 = (long)blockIdx.y * 128;
  f32x4 acc[4][4] = {};
  for (int k0 = 0; k0 < K; k0 += 32) {
    #pragma unroll
    for (int it = 0; it < 2; ++it) {
      int idx = it * 256 + t;
      int row = idx >> 2, ch = idx & 3;   // 4x16B chunks per 64B row
      gload16(A + (m0 + row) * K + k0 + ch * 8, As + (size_t)(it * 256 + wid * 64) * 8);
      gload16(B + (n0 + row) * K + k0 + ch * 8, Bs + (size_t)(it * 256 + wid * 64) * 8);
    }
    __syncthreads();
    bf16x8 af[4], bfr[4];
    #pragma unroll
    for (int mf = 0; mf < 4; ++mf)
      af[mf] = *(const bf16x8*)(As + (wr * 64 + mf * 16 + l15) * 32 + l4 * 8);
    #pragma unroll
    for (int nf = 0; nf < 4; ++nf)
      bfr[nf] = *(const bf16x8*)(Bs + (wc * 64 + nf * 16 + l15) * 32 + l4 * 8);
    #pragma unroll
    for (int mf = 0; mf < 4; ++mf)
      #pragma unroll
      for (int nf = 0; nf < 4; ++nf)
        acc[mf][nf] = mfma16(af[mf], bfr[nf], acc[mf][nf]);
    __syncthreads();
  }
  #pragma unroll
  for (int mf = 0; mf < 4; ++mf)
    #pragma unroll
    for (int nf = 0; nf < 4; ++nf)
      #pragma unroll
      for (int i = 0; i < 4; ++i) {
        long r = m0 + wr * 64 + mf * 16 + l4 * 4 + i;
        long c = n0 + wc * 64 + nf * 16 + l15;
        if (OUT_BF16) ((bf16_t*)Cout)[r * N + c] = (bf16_t)acc[mf][nf][i];
        else          ((float*)Cout)[r * N + c] = acc[mf][nf][i];
      }
}

// ---------------- RoPE (rot_dim=32) + q-scale, in-place on qkv[4096][6144] ----------------
__global__ __launch_bounds__(256) void rope_scale(bf16_t* __restrict__ qkv) {
  int t = blockIdx.x * 256 + threadIdx.x;    // [0, 4096*256)
  int m = t >> 8;
  int h = (t >> 4) & 15;
  int j = t & 15;
  int n = m & 2047;
  const float L2_10000_D16 = 0.8304820237218406f;  // log2(10000)/16
  float inv = exp2f(-(float)j * L2_10000_D16);     // 10000^(-j/16)
  float ang = (float)n * inv;
  float s, c;
  sincosf(ang, &s, &c);
  const float scale = 0.08838834764831845f;        // 128^-0.5
  bf16_t* qp = qkv + (long)m * 6144 + h * 128;
  float a = (float)qp[j], b = (float)qp[j + 16];
  qp[j]      = (bf16_t)((a * c - b * s) * scale);
  qp[j + 16] = (bf16_t)((b * c + a * s) * scale);
  #pragma unroll
  for (int u = 0; u < 6; ++u) {
    int d = 32 + j + u * 16;
    qp[d] = (bf16_t)((float)qp[d] * scale);
  }
  bf16_t* kp = qp + 2048;
  a = (float)kp[j]; b = (float)kp[j + 16];
  kp[j]      = (bf16_t)(a * c - b * s);
  kp[j + 16] = (bf16_t)(b * c + a * s);
}

// ---------------- causal flash attention (swapped-QK^T, 8 waves, QBLK=16) ----------------
__global__ __launch_bounds__(512, 4) void attn_causal(const bf16_t* __restrict__ qkv,
                                                      bf16_t* __restrict__ ao) {
  const int id = blockIdx.x;
  const int qt = 15 - (id >> 5);             // LPT: longest first
  const int bh = id & 31;
  const int b = bh >> 4, h = bh & 15;
  const int t = threadIdx.x;
  const int wid = t >> 6, l = t & 63;
  const int l15 = l & 15, l4 = l >> 4;
  __shared__ __align__(16) bf16_t Ks0[64 * 128];
  __shared__ __align__(16) bf16_t Ks1[64 * 128];
  __shared__ __align__(16) bf16_t Vt[128 * 64];
  __shared__ __align__(16) bf16_t Pb[8][16 * 72];
  const bf16_t* base = qkv + (long)b * 2048 * 6144 + h * 128;
  const int q0w = qt * 128 + wid * 16;
  bf16x8 qf[4];
  #pragma unroll
  for (int ks = 0; ks < 4; ++ks)
    qf[ks] = *(const bf16x8*)(base + (long)(q0w + l15) * 6144 + ks * 32 + l4 * 8);
  f32x4 o[8] = {};
  float mrun = -1.0e30f, lrun = 0.f;
  bf16_t* pbuf = Pb[wid];
  bf16x8 vr0, vr1;
  const int ntiles = 2 * qt + 2;

  auto stageK = [&](int tile, bf16_t* dst) {
    const bf16_t* src = base + 2048 + (long)tile * 64 * 6144;
    #pragma unroll
    for (int it = 0; it < 2; ++it) {
      int s = it * 512 + t;                  // 16B chunk id, 0..1023
      int krow = s >> 4, kc = s & 15;
      int ksc = kc ^ (krow & 7);             // pre-swizzled source column
      gload16(src + (long)krow * 6144 + ksc * 8, dst + (size_t)s * 8);
    }
  };
  auto loadV = [&](int tile) {
    const bf16_t* vsr = base + 4096 + (long)(tile * 64 + l) * 6144;
    vr0 = *(const bf16x8*)(vsr + wid * 8);
    vr1 = *(const bf16x8*)(vsr + (8 + wid) * 8);
  };
  auto writeVt = [&]() {
    #pragma unroll
    for (int it = 0; it < 2; ++it) {
      int c = it * 8 + wid;
      bf16x8 v = it ? vr1 : vr0;
      #pragma unroll
      for (int e = 0; e < 8; ++e) {
        int d = c * 8 + e;
        Vt[d * 64 + (((l >> 3) ^ e) * 8) + (l & 7)] = v[e];
      }
    }
  };
  auto compute = [&](int kv0, const bf16_t* ksb) {
    if (kv0 > q0w + 15) return;
    f32x4 sa[4] = {};
    __builtin_amdgcn_s_setprio(1);
    #pragma unroll
    for (int ks = 0; ks < 4; ++ks) {
      #pragma unroll
      for (int nb = 0; nb < 4; ++nb) {
        int row = nb * 16 + l15;
        int cs = (ks * 4 + l4) ^ (row & 7);
        bf16x8 kf = *(const bf16x8*)(ksb + row * 128 + cs * 8);
        sa[nb] = mfma16(kf, qf[ks], sa[nb]);   // S^T: row=kv, col=q
      }
    }
    __builtin_amdgcn_s_setprio(0);
    if (kv0 + 63 > q0w) {
      const int q = q0w + l15;
      #pragma unroll
      for (int nb = 0; nb < 4; ++nb)
        #pragma unroll
        for (int i = 0; i < 4; ++i)
          if (kv0 + nb * 16 + l4 * 4 + i > q) sa[nb][i] = -3.0e38f;
    }
    f32x4 mv;
    #pragma unroll
    for (int i = 0; i < 4; ++i)
      mv[i] = fmaxf(fmaxf(sa[0][i], sa[1][i]), fmaxf(sa[2][i], sa[3][i]));
    float pmax = fmaxf(fmaxf(mv[0], mv[1]), fmaxf(mv[2], mv[3]));
    pmax = fmaxf(pmax, __shfl_xor(pmax, 16));
    pmax = fmaxf(pmax, __shfl_xor(pmax, 32));
    if (!__all(pmax - mrun <= 8.0f)) {
      float mnew = fmaxf(mrun, pmax);
      float corr = __expf(mrun - mnew);
      mrun = mnew;
      lrun *= corr;
      float cc[4];
      #pragma unroll
      for (int i = 0; i < 4; ++i) cc[i] = __shfl(corr, l4 * 4 + i);
      #pragma unroll
      for (int nf = 0; nf < 8; ++nf)
        #pragma unroll
        for (int i = 0; i < 4; ++i) o[nf][i] *= cc[i];
    }
    float ps = 0.f;
    #pragma unroll
    for (int nb = 0; nb < 4; ++nb)
      #pragma unroll
      for (int i = 0; i < 4; ++i) {
        float p = __expf(sa[nb][i] - mrun);
        sa[nb][i] = p;
        ps += p;
      }
    ps += __shfl_xor(ps, 16);
    ps += __shfl_xor(ps, 32);
    lrun += ps;
    #pragma unroll
    for (int nb = 0; nb < 4; ++nb) {
      int cw = (nb * 2 + (l4 >> 1)) ^ (l15 & 7);
      uint32_t* dst = (uint32_t*)(pbuf + l15 * 72 + cw * 8 + (l4 & 1) * 4);
      dst[0] = pack2(sa[nb][0], sa[nb][1]);
      dst[1] = pack2(sa[nb][2], sa[nb][3]);
    }
    #pragma unroll
    for (int ks2 = 0; ks2 < 2; ++ks2) {
      bf16x8 pf = *(const bf16x8*)(pbuf + l15 * 72 + (((ks2 * 4 + l4) ^ (l15 & 7)) * 8));
      __builtin_amdgcn_s_setprio(1);
      #pragma unroll
      for (int nf = 0; nf < 8; ++nf) {
        int row = nf * 16 + l15;
        bf16x8 vf = *(const bf16x8*)(Vt + row * 64 + (((ks2 * 4 + l4) ^ (row & 7)) * 8));
        o[nf] = mfma16(pf, vf, o[nf]);
      }
      __builtin_amdgcn_s_setprio(0);
    }
  };

  stageK(0, Ks0);
  loadV(0);
  writeVt();
  __syncthreads();
  for (int tile = 0; tile < ntiles; ++tile) {
    bf16_t* cur = (tile & 1) ? Ks1 : Ks0;
    bf16_t* nxt = (tile & 1) ? Ks0 : Ks1;
    const bool pre = (tile + 1 < ntiles);
    if (pre) { stageK(tile + 1, nxt); loadV(tile + 1); }
    compute(tile * 64, cur);
    __syncthreads();
    if (pre) writeVt();
    __syncthreads();
  }
  float linv = 1.f / lrun;
  float li[4];
  #pragma unroll
  for (int i = 0; i < 4; ++i) li[i] = __shfl(linv, l4 * 4 + i);
  bf16_t* aob = ao + (long)b * 2048 * 2048 + h * 128;
  #pragma unroll
  for (int i = 0; i < 4; ++i) {
    long qrow = q0w + l4 * 4 + i;
    #pragma unroll
    for (int nf = 0; nf < 8; ++nf)
      aob[qrow * 2048 + nf * 16 + l15] = (bf16_t)(o[nf][i] * li[i]);
  }
}

// ---------------- launch ----------------
extern "C" void kernel_launch(void* const* d_in, const int* in_sizes, int n_in,
                              void* d_out, int out_size, void* d_ws, size_t ws_size,
                              hipStream_t stream) {
  const float* x     = (const float*)d_in[0];
  const float* w_qkv = (const float*)d_in[1];
  const float* w_out = (const float*)d_in[2];
  char* ws = (char*)d_ws;
  bf16_t* xb    = (bf16_t*)(ws + 0L);           // 16 MiB  (4096x2048)
  bf16_t* wqkvb = (bf16_t*)(ws + 16777216L);    // 24 MiB  (6144x2048)
  bf16_t* woutb = (bf16_t*)(ws + 41943040L);    //  8 MiB  (2048x2048)
  bf16_t* qkv   = (bf16_t*)(ws + 50331648L);    // 48 MiB  (4096x6144)
  bf16_t* ao    = (bf16_t*)(ws + 100663296L);   // 16 MiB  (4096x2048) -> end 112 MiB

  cast_f32_to_bf16<<<2048, 256, 0, stream>>>(x, xb, 1048576);
  cast_f32_to_bf16<<<2048, 256, 0, stream>>>(w_qkv, wqkvb, 1572864);
  cast_f32_to_bf16<<<1024, 256, 0, stream>>>(w_out, woutb, 524288);
  // qkv[m][f] = sum_c x[m][c] * w_qkv[f][c]  — 8-phase 256^2
  gemm8p_bt<<<dim3(16, 24), 512, 0, stream>>>(xb, wqkvb, qkv, 4096, 6144, 2048);
  rope_scale<<<4096, 256, 0, stream>>>(qkv);
  attn_causal<<<512, 512, 0, stream>>>(qkv, ao);
  // out[m][c] = sum_f ao[m][f] * w_out[c][f]
  gemm_bt<false><<<dim3(32, 16), 256, 0, stream>>>(ao, woutb, d_out, 4096, 2048, 2048);
}

// Round 6
// 267.233 us; speedup vs baseline: 1.4315x; 1.0684x over previous
//
#include <hip/hip_runtime.h>
#include <hip/hip_bf16.h>
#include <stdint.h>

typedef __bf16 bf16_t;
typedef __bf16 bf16x8 __attribute__((ext_vector_type(8)));
typedef float  f32x4  __attribute__((ext_vector_type(4)));

__device__ __forceinline__ void gload16(const void* gp, void* lp) {
  __builtin_amdgcn_global_load_lds(
      (const __attribute__((address_space(1))) void*)(uintptr_t)gp,
      (__attribute__((address_space(3))) void*)(uintptr_t)lp,
      16, 0, 0);
}

__device__ __forceinline__ f32x4 mfma16(bf16x8 a, bf16x8 b, f32x4 c) {
  return __builtin_amdgcn_mfma_f32_16x16x32_bf16(a, b, c, 0, 0, 0);
}

__device__ __forceinline__ uint32_t pack2(float a, float b) {
  uint16_t ba = __builtin_bit_cast(uint16_t, (bf16_t)a);
  uint16_t bb = __builtin_bit_cast(uint16_t, (bf16_t)b);
  return (uint32_t)ba | ((uint32_t)bb << 16);
}

// ---------------- fp32 -> bf16 cast (memory-bound, vectorized) ----------------
__global__ __launch_bounds__(256) void cast_f32_to_bf16(const float* __restrict__ in,
                                                        bf16_t* __restrict__ out, int n8) {
  int i = blockIdx.x * 256 + threadIdx.x;
  int stride = gridDim.x * 256;
  for (; i < n8; i += stride) {
    const f32x4* p = (const f32x4*)in + (size_t)i * 2;
    f32x4 a = p[0], b = p[1];
    bf16x8 o;
    o[0] = (bf16_t)a[0]; o[1] = (bf16_t)a[1]; o[2] = (bf16_t)a[2]; o[3] = (bf16_t)a[3];
    o[4] = (bf16_t)b[0]; o[5] = (bf16_t)b[1]; o[6] = (bf16_t)b[2]; o[7] = (bf16_t)b[3];
    ((bf16x8*)out)[i] = o;
  }
}

// ======== 2-phase/K-tile 128x256 GEMM, C[m][n] = sum_k A[m][k]*B[n][k] ========
// 512 thr = 8 waves (2M x 4N); per-wave C = 64x64 (acc[4][4]). BK=64, double-buffered
// (96 KiB LDS). Per phase: ds_read frags + stage (gload_lds) + barrier + lgkm(0) +
// 16 MFMA + barrier. Counted vmcnt(4) at the K-tile boundary only.
// LDS swizzle: 16B-chunk ^= (row&7) on gload source AND ds_read (rule #21).
// A(kt+1) staged at P1 (opposite buffer, reads done at kt-1); B(kt+2) staged at P2
// (same buffer; B(kt) fragments are in regs after P1's end barrier) -> race-free.
template<bool OUT_BF16>
__global__ __launch_bounds__(512, 2) void gemm8p_bt(const bf16_t* __restrict__ A,
                                                    const bf16_t* __restrict__ B,
                                                    void* __restrict__ Cout,
                                                    int M, int N, int K) {
  __shared__ __align__(16) bf16_t As[2][128 * 64];
  __shared__ __align__(16) bf16_t Bs[2][256 * 64];
  const int t = threadIdx.x;
  const int wid = t >> 6, l = t & 63;
  const int l15 = l & 15, l4 = l >> 4;
  const int wm = wid >> 2, wn = wid & 3;
  const long m0 = (long)blockIdx.x * 128;
  const long n0 = (long)blockIdx.y * 256;
  const int KT = K >> 6;

  auto stageA = [&](int kt, bf16_t* __restrict__ LB) {
    #pragma unroll
    for (int it = 0; it < 2; ++it) {
      int s = it * 512 + t;          // 16B chunk id, 0..1023 (128 rows x 8 chunks)
      int r = s >> 3, c = s & 7;
      gload16(A + (m0 + r) * (long)K + kt * 64 + ((c ^ (r & 7)) << 3),
              LB + r * 64 + c * 8);
    }
  };
  auto stageB = [&](int kt, bf16_t* __restrict__ LB) {
    #pragma unroll
    for (int it = 0; it < 4; ++it) {
      int s = it * 512 + t;          // 0..2047 (256 rows x 8 chunks)
      int r = s >> 3, c = s & 7;
      gload16(B + (n0 + r) * (long)K + kt * 64 + ((c ^ (r & 7)) << 3),
              LB + r * 64 + c * 8);
    }
  };
  auto ldfrag = [&](const bf16_t* buf, int rloc, int kk) -> bf16x8 {
    return *(const bf16x8*)(buf + rloc * 64 + ((((kk << 2) + l4) ^ (rloc & 7)) << 3));
  };

  f32x4 acc[4][4] = {};

  // prologue: B0, A0, B1 ; wait for tile0 (leave B1's 4 loads in flight)
  stageB(0, &Bs[0][0]);
  stageA(0, &As[0][0]);
  stageB(1, &Bs[1][0]);
  asm volatile("s_waitcnt vmcnt(4)" ::: "memory");
  asm volatile("s_barrier" ::: "memory");

  for (int kt = 0; kt < KT; ++kt) {
    const bf16_t* Ab = &As[kt & 1][0];
    const bf16_t* Bb = &Bs[kt & 1][0];
    const bool stA = (kt + 1 < KT), stB = (kt + 2 < KT);

    // ---- P1: B-frags (8) + A mr0,1 (4); stage A(kt+1) into opposite buffer
    bf16x8 bfr[4][2];
    #pragma unroll
    for (int nr = 0; nr < 4; ++nr)
      #pragma unroll
      for (int kk = 0; kk < 2; ++kk)
        bfr[nr][kk] = ldfrag(Bb, wn * 64 + nr * 16 + l15, kk);
    {
      bf16x8 a00 = ldfrag(Ab, wm * 64 + 0 * 16 + l15, 0);
      bf16x8 a01 = ldfrag(Ab, wm * 64 + 0 * 16 + l15, 1);
      bf16x8 a10 = ldfrag(Ab, wm * 64 + 1 * 16 + l15, 0);
      bf16x8 a11 = ldfrag(Ab, wm * 64 + 1 * 16 + l15, 1);
      if (stA) stageA(kt + 1, &As[(kt + 1) & 1][0]);
      asm volatile("s_barrier" ::: "memory");
      asm volatile("s_waitcnt lgkmcnt(0)" ::: "memory");
      __builtin_amdgcn_sched_barrier(0);
      __builtin_amdgcn_s_setprio(1);
      #pragma unroll
      for (int nr = 0; nr < 4; ++nr) {
        acc[0][nr] = mfma16(a00, bfr[nr][0], acc[0][nr]);
        acc[0][nr] = mfma16(a01, bfr[nr][1], acc[0][nr]);
        acc[1][nr] = mfma16(a10, bfr[nr][0], acc[1][nr]);
        acc[1][nr] = mfma16(a11, bfr[nr][1], acc[1][nr]);
      }
      __builtin_amdgcn_s_setprio(0);
      asm volatile("s_barrier" ::: "memory");
    }
    // ---- P2: A mr2,3; stage B(kt+2) (same-parity buffer, safe after P1 barrier)
    {
      bf16x8 a00 = ldfrag(Ab, wm * 64 + 2 * 16 + l15, 0);
      bf16x8 a01 = ldfrag(Ab, wm * 64 + 2 * 16 + l15, 1);
      bf16x8 a10 = ldfrag(Ab, wm * 64 + 3 * 16 + l15, 0);
      bf16x8 a11 = ldfrag(Ab, wm * 64 + 3 * 16 + l15, 1);
      if (stB) stageB(kt + 2, &Bs[kt & 1][0]);
      asm volatile("s_barrier" ::: "memory");
      asm volatile("s_waitcnt lgkmcnt(0)" ::: "memory");
      __builtin_amdgcn_sched_barrier(0);
      __builtin_amdgcn_s_setprio(1);
      #pragma unroll
      for (int nr = 0; nr < 4; ++nr) {
        acc[2][nr] = mfma16(a00, bfr[nr][0], acc[2][nr]);
        acc[2][nr] = mfma16(a01, bfr[nr][1], acc[2][nr]);
        acc[3][nr] = mfma16(a10, bfr[nr][0], acc[3][nr]);
        acc[3][nr] = mfma16(a11, bfr[nr][1], acc[3][nr]);
      }
      __builtin_amdgcn_s_setprio(0);
      if (stB) asm volatile("s_waitcnt vmcnt(4)" ::: "memory");  // A(kt+1),B(kt+1) landed
      else     asm volatile("s_waitcnt vmcnt(0)" ::: "memory");  // tail drain
      asm volatile("s_barrier" ::: "memory");
    }
  }

  // epilogue: C/D layout col=l15, row=l4*4+i (m89-verified)
  #pragma unroll
  for (int mr = 0; mr < 4; ++mr)
    #pragma unroll
    for (int nr = 0; nr < 4; ++nr)
      #pragma unroll
      for (int i = 0; i < 4; ++i) {
        long r = m0 + wm * 64 + mr * 16 + l4 * 4 + i;
        long c = n0 + wn * 64 + nr * 16 + l15;
        if (OUT_BF16) ((bf16_t*)Cout)[r * N + c] = (bf16_t)acc[mr][nr][i];
        else          ((float*)Cout)[r * N + c] = acc[mr][nr][i];
      }
}

// ---------------- RoPE (rot_dim=32) + q-scale, in-place on qkv[4096][6144] ----------------
__global__ __launch_bounds__(256) void rope_scale(bf16_t* __restrict__ qkv) {
  int t = blockIdx.x * 256 + threadIdx.x;    // [0, 4096*256)
  int m = t >> 8;
  int h = (t >> 4) & 15;
  int j = t & 15;
  int n = m & 2047;
  const float L2_10000_D16 = 0.8304820237218406f;  // log2(10000)/16
  float inv = exp2f(-(float)j * L2_10000_D16);     // 10000^(-j/16)
  float ang = (float)n * inv;
  float s, c;
  sincosf(ang, &s, &c);
  const float scale = 0.08838834764831845f;        // 128^-0.5
  bf16_t* qp = qkv + (long)m * 6144 + h * 128;
  float a = (float)qp[j], b = (float)qp[j + 16];
  qp[j]      = (bf16_t)((a * c - b * s) * scale);
  qp[j + 16] = (bf16_t)((b * c + a * s) * scale);
  #pragma unroll
  for (int u = 0; u < 6; ++u) {
    int d = 32 + j + u * 16;
    qp[d] = (bf16_t)((float)qp[d] * scale);
  }
  bf16_t* kp = qp + 2048;
  a = (float)kp[j]; b = (float)kp[j + 16];
  kp[j]      = (bf16_t)(a * c - b * s);
  kp[j + 16] = (bf16_t)(b * c + a * s);
}

// ---------------- causal flash attention (swapped-QK^T, 8 waves, QBLK=16) ----------------
__global__ __launch_bounds__(512, 4) void attn_causal(const bf16_t* __restrict__ qkv,
                                                      bf16_t* __restrict__ ao) {
  const int id = blockIdx.x;
  const int qt = 15 - (id >> 5);             // LPT: longest first
  const int bh = id & 31;
  const int b = bh >> 4, h = bh & 15;
  const int t = threadIdx.x;
  const int wid = t >> 6, l = t & 63;
  const int l15 = l & 15, l4 = l >> 4;
  __shared__ __align__(16) bf16_t Ks0[64 * 128];
  __shared__ __align__(16) bf16_t Ks1[64 * 128];
  __shared__ __align__(16) bf16_t Vt[128 * 64];
  __shared__ __align__(16) bf16_t Pb[8][16 * 72];
  const bf16_t* base = qkv + (long)b * 2048 * 6144 + h * 128;
  const int q0w = qt * 128 + wid * 16;
  bf16x8 qf[4];
  #pragma unroll
  for (int ks = 0; ks < 4; ++ks)
    qf[ks] = *(const bf16x8*)(base + (long)(q0w + l15) * 6144 + ks * 32 + l4 * 8);
  f32x4 o[8] = {};
  float mrun = -1.0e30f, lrun = 0.f;
  bf16_t* pbuf = Pb[wid];
  bf16x8 vr0, vr1;
  const int ntiles = 2 * qt + 2;

  auto stageK = [&](int tile, bf16_t* dst) {
    const bf16_t* src = base + 2048 + (long)tile * 64 * 6144;
    #pragma unroll
    for (int it = 0; it < 2; ++it) {
      int s = it * 512 + t;                  // 16B chunk id, 0..1023
      int krow = s >> 4, kc = s & 15;
      int ksc = kc ^ (krow & 7);             // pre-swizzled source column
      gload16(src + (long)krow * 6144 + ksc * 8, dst + (size_t)s * 8);
    }
  };
  auto loadV = [&](int tile) {
    const bf16_t* vsr = base + 4096 + (long)(tile * 64 + l) * 6144;
    vr0 = *(const bf16x8*)(vsr + wid * 8);
    vr1 = *(const bf16x8*)(vsr + (8 + wid) * 8);
  };
  auto writeVt = [&]() {
    #pragma unroll
    for (int it = 0; it < 2; ++it) {
      int c = it * 8 + wid;
      bf16x8 v = it ? vr1 : vr0;
      #pragma unroll
      for (int e = 0; e < 8; ++e) {
        int d = c * 8 + e;
        Vt[d * 64 + (((l >> 3) ^ e) * 8) + (l & 7)] = v[e];
      }
    }
  };
  auto compute = [&](int kv0, const bf16_t* ksb) {
    if (kv0 > q0w + 15) return;
    f32x4 sa[4] = {};
    __builtin_amdgcn_s_setprio(1);
    #pragma unroll
    for (int ks = 0; ks < 4; ++ks) {
      #pragma unroll
      for (int nb = 0; nb < 4; ++nb) {
        int row = nb * 16 + l15;
        int cs = (ks * 4 + l4) ^ (row & 7);
        bf16x8 kf = *(const bf16x8*)(ksb + row * 128 + cs * 8);
        sa[nb] = mfma16(kf, qf[ks], sa[nb]);   // S^T: row=kv, col=q
      }
    }
    __builtin_amdgcn_s_setprio(0);
    if (kv0 + 63 > q0w) {
      const int q = q0w + l15;
      #pragma unroll
      for (int nb = 0; nb < 4; ++nb)
        #pragma unroll
        for (int i = 0; i < 4; ++i)
          if (kv0 + nb * 16 + l4 * 4 + i > q) sa[nb][i] = -3.0e38f;
    }
    f32x4 mv;
    #pragma unroll
    for (int i = 0; i < 4; ++i)
      mv[i] = fmaxf(fmaxf(sa[0][i], sa[1][i]), fmaxf(sa[2][i], sa[3][i]));
    float pmax = fmaxf(fmaxf(mv[0], mv[1]), fmaxf(mv[2], mv[3]));
    pmax = fmaxf(pmax, __shfl_xor(pmax, 16));
    pmax = fmaxf(pmax, __shfl_xor(pmax, 32));
    if (!__all(pmax - mrun <= 8.0f)) {
      float mnew = fmaxf(mrun, pmax);
      float corr = __expf(mrun - mnew);
      mrun = mnew;
      lrun *= corr;
      float cc[4];
      #pragma unroll
      for (int i = 0; i < 4; ++i) cc[i] = __shfl(corr, l4 * 4 + i);
      #pragma unroll
      for (int nf = 0; nf < 8; ++nf)
        #pragma unroll
        for (int i = 0; i < 4; ++i) o[nf][i] *= cc[i];
    }
    float ps = 0.f;
    #pragma unroll
    for (int nb = 0; nb < 4; ++nb)
      #pragma unroll
      for (int i = 0; i < 4; ++i) {
        float p = __expf(sa[nb][i] - mrun);
        sa[nb][i] = p;
        ps += p;
      }
    ps += __shfl_xor(ps, 16);
    ps += __shfl_xor(ps, 32);
    lrun += ps;
    #pragma unroll
    for (int nb = 0; nb < 4; ++nb) {
      int cw = (nb * 2 + (l4 >> 1)) ^ (l15 & 7);
      uint32_t* dst = (uint32_t*)(pbuf + l15 * 72 + cw * 8 + (l4 & 1) * 4);
      dst[0] = pack2(sa[nb][0], sa[nb][1]);
      dst[1] = pack2(sa[nb][2], sa[nb][3]);
    }
    #pragma unroll
    for (int ks2 = 0; ks2 < 2; ++ks2) {
      bf16x8 pf = *(const bf16x8*)(pbuf + l15 * 72 + (((ks2 * 4 + l4) ^ (l15 & 7)) * 8));
      __builtin_amdgcn_s_setprio(1);
      #pragma unroll
      for (int nf = 0; nf < 8; ++nf) {
        int row = nf * 16 + l15;
        bf16x8 vf = *(const bf16x8*)(Vt + row * 64 + (((ks2 * 4 + l4) ^ (row & 7)) * 8));
        o[nf] = mfma16(pf, vf, o[nf]);
      }
      __builtin_amdgcn_s_setprio(0);
    }
  };

  stageK(0, Ks0);
  loadV(0);
  writeVt();
  __syncthreads();
  for (int tile = 0; tile < ntiles; ++tile) {
    bf16_t* cur = (tile & 1) ? Ks1 : Ks0;
    bf16_t* nxt = (tile & 1) ? Ks0 : Ks1;
    const bool pre = (tile + 1 < ntiles);
    if (pre) { stageK(tile + 1, nxt); loadV(tile + 1); }
    compute(tile * 64, cur);
    __syncthreads();
    if (pre) writeVt();
    __syncthreads();
  }
  float linv = 1.f / lrun;
  float li[4];
  #pragma unroll
  for (int i = 0; i < 4; ++i) li[i] = __shfl(linv, l4 * 4 + i);
  bf16_t* aob = ao + (long)b * 2048 * 2048 + h * 128;
  #pragma unroll
  for (int i = 0; i < 4; ++i) {
    long qrow = q0w + l4 * 4 + i;
    #pragma unroll
    for (int nf = 0; nf < 8; ++nf)
      aob[qrow * 2048 + nf * 16 + l15] = (bf16_t)(o[nf][i] * li[i]);
  }
}

// ---------------- launch ----------------
extern "C" void kernel_launch(void* const* d_in, const int* in_sizes, int n_in,
                              void* d_out, int out_size, void* d_ws, size_t ws_size,
                              hipStream_t stream) {
  const float* x     = (const float*)d_in[0];
  const float* w_qkv = (const float*)d_in[1];
  const float* w_out = (const float*)d_in[2];
  char* ws = (char*)d_ws;
  bf16_t* xb    = (bf16_t*)(ws + 0L);           // 16 MiB  (4096x2048)
  bf16_t* wqkvb = (bf16_t*)(ws + 16777216L);    // 24 MiB  (6144x2048)
  bf16_t* woutb = (bf16_t*)(ws + 41943040L);    //  8 MiB  (2048x2048)
  bf16_t* qkv   = (bf16_t*)(ws + 50331648L);    // 48 MiB  (4096x6144)
  bf16_t* ao    = (bf16_t*)(ws + 100663296L);   // 16 MiB  (4096x2048) -> end 112 MiB

  cast_f32_to_bf16<<<2048, 256, 0, stream>>>(x, xb, 1048576);
  cast_f32_to_bf16<<<2048, 256, 0, stream>>>(w_qkv, wqkvb, 1572864);
  cast_f32_to_bf16<<<1024, 256, 0, stream>>>(w_out, woutb, 524288);
  // qkv[m][f] = sum_c x[m][c] * w_qkv[f][c]  — 128x256 2-phase, 768 blocks = 3 rounds
  gemm8p_bt<true ><<<dim3(32, 24), 512, 0, stream>>>(xb, wqkvb, (void*)qkv, 4096, 6144, 2048);
  rope_scale<<<4096, 256, 0, stream>>>(qkv);
  attn_causal<<<512, 512, 0, stream>>>(qkv, ao);
  // out[m][c] = sum_f ao[m][f] * w_out[c][f]  — 256 blocks = 1 round
  gemm8p_bt<false><<<dim3(32, 8), 512, 0, stream>>>(ao, woutb, d_out, 4096, 2048, 2048);
}

// Round 7
// 260.112 us; speedup vs baseline: 1.4707x; 1.0274x over previous
//
#include <hip/hip_runtime.h>
#include <hip/hip_bf16.h>
#include <stdint.h>

typedef __bf16 bf16_t;
typedef __bf16 bf16x8 __attribute__((ext_vector_type(8)));
typedef float  f32x4  __attribute__((ext_vector_type(4)));

__device__ __forceinline__ void gload16(const void* gp, void* lp) {
  __builtin_amdgcn_global_load_lds(
      (const __attribute__((address_space(1))) void*)(uintptr_t)gp,
      (__attribute__((address_space(3))) void*)(uintptr_t)lp,
      16, 0, 0);
}

__device__ __forceinline__ f32x4 mfma16(bf16x8 a, bf16x8 b, f32x4 c) {
  return __builtin_amdgcn_mfma_f32_16x16x32_bf16(a, b, c, 0, 0, 0);
}

__device__ __forceinline__ uint32_t pack2(float a, float b) {
  uint16_t ba = __builtin_bit_cast(uint16_t, (bf16_t)a);
  uint16_t bb = __builtin_bit_cast(uint16_t, (bf16_t)b);
  return (uint32_t)ba | ((uint32_t)bb << 16);
}

// ---------------- fp32 -> bf16 cast (memory-bound, vectorized) ----------------
__global__ __launch_bounds__(256) void cast_f32_to_bf16(const float* __restrict__ in,
                                                        bf16_t* __restrict__ out, int n8) {
  int i = blockIdx.x * 256 + threadIdx.x;
  int stride = gridDim.x * 256;
  for (; i < n8; i += stride) {
    const f32x4* p = (const f32x4*)in + (size_t)i * 2;
    f32x4 a = p[0], b = p[1];
    bf16x8 o;
    o[0] = (bf16_t)a[0]; o[1] = (bf16_t)a[1]; o[2] = (bf16_t)a[2]; o[3] = (bf16_t)a[3];
    o[4] = (bf16_t)b[0]; o[5] = (bf16_t)b[1]; o[6] = (bf16_t)b[2]; o[7] = (bf16_t)b[3];
    ((bf16x8*)out)[i] = o;
  }
}

// ======== 256x192 GEMM (gemm1), C[m][n] = sum_k A[m][k]*B[n][k] ========
// 512 thr = 8 waves (4M x 2N); per-wave C = 64x96 (acc[4][6]). BK=64, dbuf (112 KiB).
// Higher FLOP/LDS-byte (29 F/B) than 128x256 (23.8): reads/K-tile/wave = 12 B + 8 A.
// Same verified 2-phase counted-vmcnt skeleton as round 6; boundary vmcnt(3).
template<bool OUT_BF16>
__global__ __launch_bounds__(512, 2) void gemm_bt_wide(const bf16_t* __restrict__ A,
                                                       const bf16_t* __restrict__ B,
                                                       void* __restrict__ Cout,
                                                       int M, int N, int K) {
  __shared__ __align__(16) bf16_t As[2][256 * 64];
  __shared__ __align__(16) bf16_t Bs[2][192 * 64];
  const int t = threadIdx.x;
  const int wid = t >> 6, l = t & 63;
  const int l15 = l & 15, l4 = l >> 4;
  const int wm = wid >> 1, wn = wid & 1;
  const long m0 = (long)blockIdx.x * 256;
  const long n0 = (long)blockIdx.y * 192;
  const int KT = K >> 6;

  auto stageA = [&](int kt, bf16_t* __restrict__ LB) {
    #pragma unroll
    for (int it = 0; it < 4; ++it) {
      int s = it * 512 + t;          // 0..2047 (256 rows x 8 chunks)
      int r = s >> 3, c = s & 7;
      gload16(A + (m0 + r) * (long)K + kt * 64 + ((c ^ (r & 7)) << 3),
              LB + r * 64 + c * 8);
    }
  };
  auto stageB = [&](int kt, bf16_t* __restrict__ LB) {
    #pragma unroll
    for (int it = 0; it < 3; ++it) {
      int s = it * 512 + t;          // 0..1535 (192 rows x 8 chunks)
      int r = s >> 3, c = s & 7;
      gload16(B + (n0 + r) * (long)K + kt * 64 + ((c ^ (r & 7)) << 3),
              LB + r * 64 + c * 8);
    }
  };
  auto ldfrag = [&](const bf16_t* buf, int rloc, int kk) -> bf16x8 {
    return *(const bf16x8*)(buf + rloc * 64 + ((((kk << 2) + l4) ^ (rloc & 7)) << 3));
  };

  f32x4 acc[4][6] = {};

  // prologue: B0(3), A0(4), B1(3); vmcnt(3) -> B0,A0 landed, B1 may fly
  stageB(0, &Bs[0][0]);
  stageA(0, &As[0][0]);
  stageB(1, &Bs[1][0]);
  asm volatile("s_waitcnt vmcnt(3)" ::: "memory");
  asm volatile("s_barrier" ::: "memory");

  for (int kt = 0; kt < KT; ++kt) {
    const bf16_t* Ab = &As[kt & 1][0];
    const bf16_t* Bb = &Bs[kt & 1][0];
    const bool stA = (kt + 1 < KT), stB = (kt + 2 < KT);

    // ---- P1: all B-frags (12) + A kk0 (4); stage A(kt+1) into opposite buffer
    bf16x8 bfr[6][2];
    #pragma unroll
    for (int nr = 0; nr < 6; ++nr)
      #pragma unroll
      for (int kk = 0; kk < 2; ++kk)
        bfr[nr][kk] = ldfrag(Bb, wn * 96 + nr * 16 + l15, kk);
    {
      bf16x8 a0 = ldfrag(Ab, wm * 64 + 0 * 16 + l15, 0);
      bf16x8 a1 = ldfrag(Ab, wm * 64 + 1 * 16 + l15, 0);
      bf16x8 a2 = ldfrag(Ab, wm * 64 + 2 * 16 + l15, 0);
      bf16x8 a3 = ldfrag(Ab, wm * 64 + 3 * 16 + l15, 0);
      if (stA) stageA(kt + 1, &As[(kt + 1) & 1][0]);
      asm volatile("s_barrier" ::: "memory");
      asm volatile("s_waitcnt lgkmcnt(0)" ::: "memory");
      __builtin_amdgcn_sched_barrier(0);
      __builtin_amdgcn_s_setprio(1);
      #pragma unroll
      for (int nr = 0; nr < 6; ++nr) {
        acc[0][nr] = mfma16(a0, bfr[nr][0], acc[0][nr]);
        acc[1][nr] = mfma16(a1, bfr[nr][0], acc[1][nr]);
        acc[2][nr] = mfma16(a2, bfr[nr][0], acc[2][nr]);
        acc[3][nr] = mfma16(a3, bfr[nr][0], acc[3][nr]);
      }
      __builtin_amdgcn_s_setprio(0);
      asm volatile("s_barrier" ::: "memory");
    }
    // ---- P2: A kk1 (4); stage B(kt+2) (same-parity buffer, safe after P1 barrier)
    {
      bf16x8 a0 = ldfrag(Ab, wm * 64 + 0 * 16 + l15, 1);
      bf16x8 a1 = ldfrag(Ab, wm * 64 + 1 * 16 + l15, 1);
      bf16x8 a2 = ldfrag(Ab, wm * 64 + 2 * 16 + l15, 1);
      bf16x8 a3 = ldfrag(Ab, wm * 64 + 3 * 16 + l15, 1);
      if (stB) stageB(kt + 2, &Bs[kt & 1][0]);
      asm volatile("s_barrier" ::: "memory");
      asm volatile("s_waitcnt lgkmcnt(0)" ::: "memory");
      __builtin_amdgcn_sched_barrier(0);
      __builtin_amdgcn_s_setprio(1);
      #pragma unroll
      for (int nr = 0; nr < 6; ++nr) {
        acc[0][nr] = mfma16(a0, bfr[nr][1], acc[0][nr]);
        acc[1][nr] = mfma16(a1, bfr[nr][1], acc[1][nr]);
        acc[2][nr] = mfma16(a2, bfr[nr][1], acc[2][nr]);
        acc[3][nr] = mfma16(a3, bfr[nr][1], acc[3][nr]);
      }
      __builtin_amdgcn_s_setprio(0);
      if (stB) asm volatile("s_waitcnt vmcnt(3)" ::: "memory");  // A(kt+1),B(kt+1) landed
      else     asm volatile("s_waitcnt vmcnt(0)" ::: "memory");  // tail drain
      asm volatile("s_barrier" ::: "memory");
    }
  }

  // epilogue: C/D layout col=l15, row=l4*4+i (m89-verified)
  #pragma unroll
  for (int mr = 0; mr < 4; ++mr)
    #pragma unroll
    for (int nr = 0; nr < 6; ++nr)
      #pragma unroll
      for (int i = 0; i < 4; ++i) {
        long r = m0 + wm * 64 + mr * 16 + l4 * 4 + i;
        long c = n0 + wn * 96 + nr * 16 + l15;
        if (OUT_BF16) ((bf16_t*)Cout)[r * N + c] = (bf16_t)acc[mr][nr][i];
        else          ((float*)Cout)[r * N + c] = acc[mr][nr][i];
      }
}

// ======== 128x256 GEMM (gemm2), verified round-6 structure ========
template<bool OUT_BF16>
__global__ __launch_bounds__(512, 2) void gemm8p_bt(const bf16_t* __restrict__ A,
                                                    const bf16_t* __restrict__ B,
                                                    void* __restrict__ Cout,
                                                    int M, int N, int K) {
  __shared__ __align__(16) bf16_t As[2][128 * 64];
  __shared__ __align__(16) bf16_t Bs[2][256 * 64];
  const int t = threadIdx.x;
  const int wid = t >> 6, l = t & 63;
  const int l15 = l & 15, l4 = l >> 4;
  const int wm = wid >> 2, wn = wid & 3;
  const long m0 = (long)blockIdx.x * 128;
  const long n0 = (long)blockIdx.y * 256;
  const int KT = K >> 6;

  auto stageA = [&](int kt, bf16_t* __restrict__ LB) {
    #pragma unroll
    for (int it = 0; it < 2; ++it) {
      int s = it * 512 + t;
      int r = s >> 3, c = s & 7;
      gload16(A + (m0 + r) * (long)K + kt * 64 + ((c ^ (r & 7)) << 3),
              LB + r * 64 + c * 8);
    }
  };
  auto stageB = [&](int kt, bf16_t* __restrict__ LB) {
    #pragma unroll
    for (int it = 0; it < 4; ++it) {
      int s = it * 512 + t;
      int r = s >> 3, c = s & 7;
      gload16(B + (n0 + r) * (long)K + kt * 64 + ((c ^ (r & 7)) << 3),
              LB + r * 64 + c * 8);
    }
  };
  auto ldfrag = [&](const bf16_t* buf, int rloc, int kk) -> bf16x8 {
    return *(const bf16x8*)(buf + rloc * 64 + ((((kk << 2) + l4) ^ (rloc & 7)) << 3));
  };

  f32x4 acc[4][4] = {};

  stageB(0, &Bs[0][0]);
  stageA(0, &As[0][0]);
  stageB(1, &Bs[1][0]);
  asm volatile("s_waitcnt vmcnt(4)" ::: "memory");
  asm volatile("s_barrier" ::: "memory");

  for (int kt = 0; kt < KT; ++kt) {
    const bf16_t* Ab = &As[kt & 1][0];
    const bf16_t* Bb = &Bs[kt & 1][0];
    const bool stA = (kt + 1 < KT), stB = (kt + 2 < KT);

    bf16x8 bfr[4][2];
    #pragma unroll
    for (int nr = 0; nr < 4; ++nr)
      #pragma unroll
      for (int kk = 0; kk < 2; ++kk)
        bfr[nr][kk] = ldfrag(Bb, wn * 64 + nr * 16 + l15, kk);
    {
      bf16x8 a00 = ldfrag(Ab, wm * 64 + 0 * 16 + l15, 0);
      bf16x8 a01 = ldfrag(Ab, wm * 64 + 0 * 16 + l15, 1);
      bf16x8 a10 = ldfrag(Ab, wm * 64 + 1 * 16 + l15, 0);
      bf16x8 a11 = ldfrag(Ab, wm * 64 + 1 * 16 + l15, 1);
      if (stA) stageA(kt + 1, &As[(kt + 1) & 1][0]);
      asm volatile("s_barrier" ::: "memory");
      asm volatile("s_waitcnt lgkmcnt(0)" ::: "memory");
      __builtin_amdgcn_sched_barrier(0);
      __builtin_amdgcn_s_setprio(1);
      #pragma unroll
      for (int nr = 0; nr < 4; ++nr) {
        acc[0][nr] = mfma16(a00, bfr[nr][0], acc[0][nr]);
        acc[0][nr] = mfma16(a01, bfr[nr][1], acc[0][nr]);
        acc[1][nr] = mfma16(a10, bfr[nr][0], acc[1][nr]);
        acc[1][nr] = mfma16(a11, bfr[nr][1], acc[1][nr]);
      }
      __builtin_amdgcn_s_setprio(0);
      asm volatile("s_barrier" ::: "memory");
    }
    {
      bf16x8 a00 = ldfrag(Ab, wm * 64 + 2 * 16 + l15, 0);
      bf16x8 a01 = ldfrag(Ab, wm * 64 + 2 * 16 + l15, 1);
      bf16x8 a10 = ldfrag(Ab, wm * 64 + 3 * 16 + l15, 0);
      bf16x8 a11 = ldfrag(Ab, wm * 64 + 3 * 16 + l15, 1);
      if (stB) stageB(kt + 2, &Bs[kt & 1][0]);
      asm volatile("s_barrier" ::: "memory");
      asm volatile("s_waitcnt lgkmcnt(0)" ::: "memory");
      __builtin_amdgcn_sched_barrier(0);
      __builtin_amdgcn_s_setprio(1);
      #pragma unroll
      for (int nr = 0; nr < 4; ++nr) {
        acc[2][nr] = mfma16(a00, bfr[nr][0], acc[2][nr]);
        acc[2][nr] = mfma16(a01, bfr[nr][1], acc[2][nr]);
        acc[3][nr] = mfma16(a10, bfr[nr][0], acc[3][nr]);
        acc[3][nr] = mfma16(a11, bfr[nr][1], acc[3][nr]);
      }
      __builtin_amdgcn_s_setprio(0);
      if (stB) asm volatile("s_waitcnt vmcnt(4)" ::: "memory");
      else     asm volatile("s_waitcnt vmcnt(0)" ::: "memory");
      asm volatile("s_barrier" ::: "memory");
    }
  }

  #pragma unroll
  for (int mr = 0; mr < 4; ++mr)
    #pragma unroll
    for (int nr = 0; nr < 4; ++nr)
      #pragma unroll
      for (int i = 0; i < 4; ++i) {
        long r = m0 + wm * 64 + mr * 16 + l4 * 4 + i;
        long c = n0 + wn * 64 + nr * 16 + l15;
        if (OUT_BF16) ((bf16_t*)Cout)[r * N + c] = (bf16_t)acc[mr][nr][i];
        else          ((float*)Cout)[r * N + c] = acc[mr][nr][i];
      }
}

// ---------------- RoPE (rot_dim=32) + q-scale, in-place on qkv[4096][6144] ----------------
__global__ __launch_bounds__(256) void rope_scale(bf16_t* __restrict__ qkv) {
  int t = blockIdx.x * 256 + threadIdx.x;    // [0, 4096*256)
  int m = t >> 8;
  int h = (t >> 4) & 15;
  int j = t & 15;
  int n = m & 2047;
  const float L2_10000_D16 = 0.8304820237218406f;  // log2(10000)/16
  float inv = exp2f(-(float)j * L2_10000_D16);     // 10000^(-j/16)
  float ang = (float)n * inv;
  float s, c;
  sincosf(ang, &s, &c);
  const float scale = 0.08838834764831845f;        // 128^-0.5
  bf16_t* qp = qkv + (long)m * 6144 + h * 128;
  float a = (float)qp[j], b = (float)qp[j + 16];
  qp[j]      = (bf16_t)((a * c - b * s) * scale);
  qp[j + 16] = (bf16_t)((b * c + a * s) * scale);
  #pragma unroll
  for (int u = 0; u < 6; ++u) {
    int d = 32 + j + u * 16;
    qp[d] = (bf16_t)((float)qp[d] * scale);
  }
  bf16_t* kp = qp + 2048;
  a = (float)kp[j]; b = (float)kp[j + 16];
  kp[j]      = (bf16_t)(a * c - b * s);
  kp[j + 16] = (bf16_t)(b * c + a * s);
}

// ---------------- causal flash attention (swapped-QK^T, 8 waves, QBLK=16) ----------------
__global__ __launch_bounds__(512, 4) void attn_causal(const bf16_t* __restrict__ qkv,
                                                      bf16_t* __restrict__ ao) {
  const int id = blockIdx.x;
  const int qt = 15 - (id >> 5);             // LPT: longest first
  const int bh = id & 31;
  const int b = bh >> 4, h = bh & 15;
  const int t = threadIdx.x;
  const int wid = t >> 6, l = t & 63;
  const int l15 = l & 15, l4 = l >> 4;
  __shared__ __align__(16) bf16_t Ks0[64 * 128];
  __shared__ __align__(16) bf16_t Ks1[64 * 128];
  __shared__ __align__(16) bf16_t Vt[128 * 64];
  __shared__ __align__(16) bf16_t Pb[8][16 * 72];
  const bf16_t* base = qkv + (long)b * 2048 * 6144 + h * 128;
  const int q0w = qt * 128 + wid * 16;
  bf16x8 qf[4];
  #pragma unroll
  for (int ks = 0; ks < 4; ++ks)
    qf[ks] = *(const bf16x8*)(base + (long)(q0w + l15) * 6144 + ks * 32 + l4 * 8);
  f32x4 o[8] = {};
  float mrun = -1.0e30f, lrun = 0.f;
  bf16_t* pbuf = Pb[wid];
  bf16x8 vr0, vr1;
  const int ntiles = 2 * qt + 2;

  auto stageK = [&](int tile, bf16_t* dst) {
    const bf16_t* src = base + 2048 + (long)tile * 64 * 6144;
    #pragma unroll
    for (int it = 0; it < 2; ++it) {
      int s = it * 512 + t;
      int krow = s >> 4, kc = s & 15;
      int ksc = kc ^ (krow & 7);
      gload16(src + (long)krow * 6144 + ksc * 8, dst + (size_t)s * 8);
    }
  };
  auto loadV = [&](int tile) {
    const bf16_t* vsr = base + 4096 + (long)(tile * 64 + l) * 6144;
    vr0 = *(const bf16x8*)(vsr + wid * 8);
    vr1 = *(const bf16x8*)(vsr + (8 + wid) * 8);
  };
  auto writeVt = [&]() {
    #pragma unroll
    for (int it = 0; it < 2; ++it) {
      int c = it * 8 + wid;
      bf16x8 v = it ? vr1 : vr0;
      #pragma unroll
      for (int e = 0; e < 8; ++e) {
        int d = c * 8 + e;
        Vt[d * 64 + (((l >> 3) ^ e) * 8) + (l & 7)] = v[e];
      }
    }
  };
  auto compute = [&](int kv0, const bf16_t* ksb) {
    if (kv0 > q0w + 15) return;
    f32x4 sa[4] = {};
    __builtin_amdgcn_s_setprio(1);
    #pragma unroll
    for (int ks = 0; ks < 4; ++ks) {
      #pragma unroll
      for (int nb = 0; nb < 4; ++nb) {
        int row = nb * 16 + l15;
        int cs = (ks * 4 + l4) ^ (row & 7);
        bf16x8 kf = *(const bf16x8*)(ksb + row * 128 + cs * 8);
        sa[nb] = mfma16(kf, qf[ks], sa[nb]);   // S^T: row=kv, col=q
      }
    }
    __builtin_amdgcn_s_setprio(0);
    if (kv0 + 63 > q0w) {
      const int q = q0w + l15;
      #pragma unroll
      for (int nb = 0; nb < 4; ++nb)
        #pragma unroll
        for (int i = 0; i < 4; ++i)
          if (kv0 + nb * 16 + l4 * 4 + i > q) sa[nb][i] = -3.0e38f;
    }
    f32x4 mv;
    #pragma unroll
    for (int i = 0; i < 4; ++i)
      mv[i] = fmaxf(fmaxf(sa[0][i], sa[1][i]), fmaxf(sa[2][i], sa[3][i]));
    float pmax = fmaxf(fmaxf(mv[0], mv[1]), fmaxf(mv[2], mv[3]));
    pmax = fmaxf(pmax, __shfl_xor(pmax, 16));
    pmax = fmaxf(pmax, __shfl_xor(pmax, 32));
    if (!__all(pmax - mrun <= 8.0f)) {
      float mnew = fmaxf(mrun, pmax);
      float corr = __expf(mrun - mnew);
      mrun = mnew;
      lrun *= corr;
      float cc[4];
      #pragma unroll
      for (int i = 0; i < 4; ++i) cc[i] = __shfl(corr, l4 * 4 + i);
      #pragma unroll
      for (int nf = 0; nf < 8; ++nf)
        #pragma unroll
        for (int i = 0; i < 4; ++i) o[nf][i] *= cc[i];
    }
    float ps = 0.f;
    #pragma unroll
    for (int nb = 0; nb < 4; ++nb)
      #pragma unroll
      for (int i = 0; i < 4; ++i) {
        float p = __expf(sa[nb][i] - mrun);
        sa[nb][i] = p;
        ps += p;
      }
    ps += __shfl_xor(ps, 16);
    ps += __shfl_xor(ps, 32);
    lrun += ps;
    #pragma unroll
    for (int nb = 0; nb < 4; ++nb) {
      int cw = (nb * 2 + (l4 >> 1)) ^ (l15 & 7);
      uint32_t* dst = (uint32_t*)(pbuf + l15 * 72 + cw * 8 + (l4 & 1) * 4);
      dst[0] = pack2(sa[nb][0], sa[nb][1]);
      dst[1] = pack2(sa[nb][2], sa[nb][3]);
    }
    #pragma unroll
    for (int ks2 = 0; ks2 < 2; ++ks2) {
      bf16x8 pf = *(const bf16x8*)(pbuf + l15 * 72 + (((ks2 * 4 + l4) ^ (l15 & 7)) * 8));
      __builtin_amdgcn_s_setprio(1);
      #pragma unroll
      for (int nf = 0; nf < 8; ++nf) {
        int row = nf * 16 + l15;
        bf16x8 vf = *(const bf16x8*)(Vt + row * 64 + (((ks2 * 4 + l4) ^ (row & 7)) * 8));
        o[nf] = mfma16(pf, vf, o[nf]);
      }
      __builtin_amdgcn_s_setprio(0);
    }
  };

  stageK(0, Ks0);
  loadV(0);
  writeVt();
  __syncthreads();
  for (int tile = 0; tile < ntiles; ++tile) {
    bf16_t* cur = (tile & 1) ? Ks1 : Ks0;
    bf16_t* nxt = (tile & 1) ? Ks0 : Ks1;
    const bool pre = (tile + 1 < ntiles);
    if (pre) { stageK(tile + 1, nxt); loadV(tile + 1); }
    compute(tile * 64, cur);
    __syncthreads();
    if (pre) writeVt();
    __syncthreads();
  }
  float linv = 1.f / lrun;
  float li[4];
  #pragma unroll
  for (int i = 0; i < 4; ++i) li[i] = __shfl(linv, l4 * 4 + i);
  bf16_t* aob = ao + (long)b * 2048 * 2048 + h * 128;
  #pragma unroll
  for (int i = 0; i < 4; ++i) {
    long qrow = q0w + l4 * 4 + i;
    #pragma unroll
    for (int nf = 0; nf < 8; ++nf)
      aob[qrow * 2048 + nf * 16 + l15] = (bf16_t)(o[nf][i] * li[i]);
  }
}

// ---------------- launch ----------------
extern "C" void kernel_launch(void* const* d_in, const int* in_sizes, int n_in,
                              void* d_out, int out_size, void* d_ws, size_t ws_size,
                              hipStream_t stream) {
  const float* x     = (const float*)d_in[0];
  const float* w_qkv = (const float*)d_in[1];
  const float* w_out = (const float*)d_in[2];
  char* ws = (char*)d_ws;
  bf16_t* xb    = (bf16_t*)(ws + 0L);           // 16 MiB  (4096x2048)
  bf16_t* wqkvb = (bf16_t*)(ws + 16777216L);    // 24 MiB  (6144x2048)
  bf16_t* woutb = (bf16_t*)(ws + 41943040L);    //  8 MiB  (2048x2048)
  bf16_t* qkv   = (bf16_t*)(ws + 50331648L);    // 48 MiB  (4096x6144)
  bf16_t* ao    = (bf16_t*)(ws + 100663296L);   // 16 MiB  (4096x2048) -> end 112 MiB

  cast_f32_to_bf16<<<2048, 256, 0, stream>>>(x, xb, 1048576);
  cast_f32_to_bf16<<<2048, 256, 0, stream>>>(w_qkv, wqkvb, 1572864);
  cast_f32_to_bf16<<<1024, 256, 0, stream>>>(w_out, woutb, 524288);
  // qkv[m][f] = sum_c x[m][c] * w_qkv[f][c]  — 256x192, 512 blocks = 2 exact rounds
  gemm_bt_wide<true ><<<dim3(16, 32), 512, 0, stream>>>(xb, wqkvb, (void*)qkv, 4096, 6144, 2048);
  rope_scale<<<4096, 256, 0, stream>>>(qkv);
  attn_causal<<<512, 512, 0, stream>>>(qkv, ao);
  // out[m][c] = sum_f ao[m][f] * w_out[c][f]  — 128x256, 256 blocks = 1 round
  gemm8p_bt<false><<<dim3(32, 8), 512, 0, stream>>>(ao, woutb, d_out, 4096, 2048, 2048);
}

// Round 8
// 256.312 us; speedup vs baseline: 1.4925x; 1.0148x over previous
//
#include <hip/hip_runtime.h>
#include <hip/hip_bf16.h>
#include <stdint.h>

typedef __bf16 bf16_t;
typedef __bf16 bf16x8 __attribute__((ext_vector_type(8)));
typedef float  f32x4  __attribute__((ext_vector_type(4)));

__device__ __forceinline__ void gload16(const void* gp, void* lp) {
  __builtin_amdgcn_global_load_lds(
      (const __attribute__((address_space(1))) void*)(uintptr_t)gp,
      (__attribute__((address_space(3))) void*)(uintptr_t)lp,
      16, 0, 0);
}

__device__ __forceinline__ f32x4 mfma16(bf16x8 a, bf16x8 b, f32x4 c) {
  return __builtin_amdgcn_mfma_f32_16x16x32_bf16(a, b, c, 0, 0, 0);
}

__device__ __forceinline__ uint32_t pack2(float a, float b) {
  uint16_t ba = __builtin_bit_cast(uint16_t, (bf16_t)a);
  uint16_t bb = __builtin_bit_cast(uint16_t, (bf16_t)b);
  return (uint32_t)ba | ((uint32_t)bb << 16);
}

// ---------------- fp32 -> bf16 cast (memory-bound, vectorized) ----------------
__global__ __launch_bounds__(256) void cast_f32_to_bf16(const float* __restrict__ in,
                                                        bf16_t* __restrict__ out, int n8) {
  int i = blockIdx.x * 256 + threadIdx.x;
  int stride = gridDim.x * 256;
  for (; i < n8; i += stride) {
    const f32x4* p = (const f32x4*)in + (size_t)i * 2;
    f32x4 a = p[0], b = p[1];
    bf16x8 o;
    o[0] = (bf16_t)a[0]; o[1] = (bf16_t)a[1]; o[2] = (bf16_t)a[2]; o[3] = (bf16_t)a[3];
    o[4] = (bf16_t)b[0]; o[5] = (bf16_t)b[1]; o[6] = (bf16_t)b[2]; o[7] = (bf16_t)b[3];
    ((bf16x8*)out)[i] = o;
  }
}

// ======== 256x384 GEMM (gemm1), C[m][n] = sum_k A[m][k]*B[n][k] ========
// 512 thr = 8 waves (2M x 4N); per-wave C = 128x96 (acc[8][6] = 192 VGPR). BK=32,
// dbuf 80 KiB. F/B: per-CU K-tile LDS reads 114.7 KB (1349 cy) < MFMA 1549 cy ->
// MFMA-bound cap. Grid 16x16 = 256 blocks = 1 exact dispatch round.
// BK=32 rows are exactly 4x16B chunks and frag reads consume whole rows (l4 spans
// all chunks) -> LINEAR layout is bank-conflict-free; no swizzle.
// 2-phase counted-vmcnt skeleton (round-6-verified): A(kt+1) staged in P1 to the
// opposite buffer; B(kt+2) staged in P2 (same buffer; B(kt) in regs after P1
// barrier); boundary vmcnt(3).
__global__ __launch_bounds__(512, 2) void gemm_qkv(const bf16_t* __restrict__ A,
                                                   const bf16_t* __restrict__ B,
                                                   bf16_t* __restrict__ C,
                                                   int M, int N, int K) {
  __shared__ __align__(16) bf16_t As[2][256 * 32];
  __shared__ __align__(16) bf16_t Bs[2][384 * 32];
  const int t = threadIdx.x;
  const int wid = t >> 6, l = t & 63;
  const int l15 = l & 15, l4 = l >> 4;
  const int wm = wid >> 2, wn = wid & 3;
  const long m0 = (long)blockIdx.x * 256;
  const long n0 = (long)blockIdx.y * 384;
  const int KT = K >> 5;

  auto stageA = [&](int kt, bf16_t* __restrict__ LB) {
    #pragma unroll
    for (int it = 0; it < 2; ++it) {
      int s = it * 512 + t;          // 0..1023 (256 rows x 4 chunks)
      int r = s >> 2, c = s & 3;
      gload16(A + (m0 + r) * (long)K + kt * 32 + c * 8, LB + r * 32 + c * 8);
    }
  };
  auto stageB = [&](int kt, bf16_t* __restrict__ LB) {
    #pragma unroll
    for (int it = 0; it < 3; ++it) {
      int s = it * 512 + t;          // 0..1535 (384 rows x 4 chunks)
      int r = s >> 2, c = s & 3;
      gload16(B + (n0 + r) * (long)K + kt * 32 + c * 8, LB + r * 32 + c * 8);
    }
  };
  auto ldfrag = [&](const bf16_t* buf, int rloc) -> bf16x8 {
    return *(const bf16x8*)(buf + rloc * 32 + l4 * 8);
  };

  f32x4 acc[8][6] = {};

  // prologue: B0(3), A0(2), B1(3); vmcnt(3) -> B0,A0 landed, B1 in flight
  stageB(0, &Bs[0][0]);
  stageA(0, &As[0][0]);
  stageB(1, &Bs[1][0]);
  asm volatile("s_waitcnt vmcnt(3)" ::: "memory");
  asm volatile("s_barrier" ::: "memory");

  for (int kt = 0; kt < KT; ++kt) {
    const bf16_t* Ab = &As[kt & 1][0];
    const bf16_t* Bb = &Bs[kt & 1][0];
    const bool stA = (kt + 1 < KT), stB = (kt + 2 < KT);

    // ---- P1: all 6 B-frags + A mr0-3; stage A(kt+1) into opposite buffer
    bf16x8 bfr[6];
    #pragma unroll
    for (int nr = 0; nr < 6; ++nr) bfr[nr] = ldfrag(Bb, wn * 96 + nr * 16 + l15);
    {
      bf16x8 a0 = ldfrag(Ab, wm * 128 + 0 * 16 + l15);
      bf16x8 a1 = ldfrag(Ab, wm * 128 + 1 * 16 + l15);
      bf16x8 a2 = ldfrag(Ab, wm * 128 + 2 * 16 + l15);
      bf16x8 a3 = ldfrag(Ab, wm * 128 + 3 * 16 + l15);
      if (stA) stageA(kt + 1, &As[(kt + 1) & 1][0]);
      asm volatile("s_barrier" ::: "memory");
      asm volatile("s_waitcnt lgkmcnt(0)" ::: "memory");
      __builtin_amdgcn_sched_barrier(0);
      __builtin_amdgcn_s_setprio(1);
      #pragma unroll
      for (int nr = 0; nr < 6; ++nr) {
        acc[0][nr] = mfma16(a0, bfr[nr], acc[0][nr]);
        acc[1][nr] = mfma16(a1, bfr[nr], acc[1][nr]);
        acc[2][nr] = mfma16(a2, bfr[nr], acc[2][nr]);
        acc[3][nr] = mfma16(a3, bfr[nr], acc[3][nr]);
      }
      __builtin_amdgcn_s_setprio(0);
      asm volatile("s_barrier" ::: "memory");
    }
    // ---- P2: A mr4-7; stage B(kt+2) (same-parity buffer, safe after P1 barrier)
    {
      bf16x8 a4 = ldfrag(Ab, wm * 128 + 4 * 16 + l15);
      bf16x8 a5 = ldfrag(Ab, wm * 128 + 5 * 16 + l15);
      bf16x8 a6 = ldfrag(Ab, wm * 128 + 6 * 16 + l15);
      bf16x8 a7 = ldfrag(Ab, wm * 128 + 7 * 16 + l15);
      if (stB) stageB(kt + 2, &Bs[kt & 1][0]);
      asm volatile("s_barrier" ::: "memory");
      asm volatile("s_waitcnt lgkmcnt(0)" ::: "memory");
      __builtin_amdgcn_sched_barrier(0);
      __builtin_amdgcn_s_setprio(1);
      #pragma unroll
      for (int nr = 0; nr < 6; ++nr) {
        acc[4][nr] = mfma16(a4, bfr[nr], acc[4][nr]);
        acc[5][nr] = mfma16(a5, bfr[nr], acc[5][nr]);
        acc[6][nr] = mfma16(a6, bfr[nr], acc[6][nr]);
        acc[7][nr] = mfma16(a7, bfr[nr], acc[7][nr]);
      }
      __builtin_amdgcn_s_setprio(0);
      if (stB) asm volatile("s_waitcnt vmcnt(3)" ::: "memory");  // kt+1 landed; B(kt+2) flies
      else     asm volatile("s_waitcnt vmcnt(0)" ::: "memory");  // tail drain
      asm volatile("s_barrier" ::: "memory");
    }
  }

  // epilogue: C/D layout col=l15, row=l4*4+i (m89-verified)
  #pragma unroll
  for (int mr = 0; mr < 8; ++mr)
    #pragma unroll
    for (int nr = 0; nr < 6; ++nr)
      #pragma unroll
      for (int i = 0; i < 4; ++i) {
        long r = m0 + wm * 128 + mr * 16 + l4 * 4 + i;
        long c = n0 + wn * 96 + nr * 16 + l15;
        C[r * N + c] = (bf16_t)acc[mr][nr][i];
      }
}

// ======== 128x256 GEMM (gemm2), verified round-6 structure ========
template<bool OUT_BF16>
__global__ __launch_bounds__(512, 2) void gemm8p_bt(const bf16_t* __restrict__ A,
                                                    const bf16_t* __restrict__ B,
                                                    void* __restrict__ Cout,
                                                    int M, int N, int K) {
  __shared__ __align__(16) bf16_t As[2][128 * 64];
  __shared__ __align__(16) bf16_t Bs[2][256 * 64];
  const int t = threadIdx.x;
  const int wid = t >> 6, l = t & 63;
  const int l15 = l & 15, l4 = l >> 4;
  const int wm = wid >> 2, wn = wid & 3;
  const long m0 = (long)blockIdx.x * 128;
  const long n0 = (long)blockIdx.y * 256;
  const int KT = K >> 6;

  auto stageA = [&](int kt, bf16_t* __restrict__ LB) {
    #pragma unroll
    for (int it = 0; it < 2; ++it) {
      int s = it * 512 + t;
      int r = s >> 3, c = s & 7;
      gload16(A + (m0 + r) * (long)K + kt * 64 + ((c ^ (r & 7)) << 3),
              LB + r * 64 + c * 8);
    }
  };
  auto stageB = [&](int kt, bf16_t* __restrict__ LB) {
    #pragma unroll
    for (int it = 0; it < 4; ++it) {
      int s = it * 512 + t;
      int r = s >> 3, c = s & 7;
      gload16(B + (n0 + r) * (long)K + kt * 64 + ((c ^ (r & 7)) << 3),
              LB + r * 64 + c * 8);
    }
  };
  auto ldfrag = [&](const bf16_t* buf, int rloc, int kk) -> bf16x8 {
    return *(const bf16x8*)(buf + rloc * 64 + ((((kk << 2) + l4) ^ (rloc & 7)) << 3));
  };

  f32x4 acc[4][4] = {};

  stageB(0, &Bs[0][0]);
  stageA(0, &As[0][0]);
  stageB(1, &Bs[1][0]);
  asm volatile("s_waitcnt vmcnt(4)" ::: "memory");
  asm volatile("s_barrier" ::: "memory");

  for (int kt = 0; kt < KT; ++kt) {
    const bf16_t* Ab = &As[kt & 1][0];
    const bf16_t* Bb = &Bs[kt & 1][0];
    const bool stA = (kt + 1 < KT), stB = (kt + 2 < KT);

    bf16x8 bfr[4][2];
    #pragma unroll
    for (int nr = 0; nr < 4; ++nr)
      #pragma unroll
      for (int kk = 0; kk < 2; ++kk)
        bfr[nr][kk] = ldfrag(Bb, wn * 64 + nr * 16 + l15, kk);
    {
      bf16x8 a00 = ldfrag(Ab, wm * 64 + 0 * 16 + l15, 0);
      bf16x8 a01 = ldfrag(Ab, wm * 64 + 0 * 16 + l15, 1);
      bf16x8 a10 = ldfrag(Ab, wm * 64 + 1 * 16 + l15, 0);
      bf16x8 a11 = ldfrag(Ab, wm * 64 + 1 * 16 + l15, 1);
      if (stA) stageA(kt + 1, &As[(kt + 1) & 1][0]);
      asm volatile("s_barrier" ::: "memory");
      asm volatile("s_waitcnt lgkmcnt(0)" ::: "memory");
      __builtin_amdgcn_sched_barrier(0);
      __builtin_amdgcn_s_setprio(1);
      #pragma unroll
      for (int nr = 0; nr < 4; ++nr) {
        acc[0][nr] = mfma16(a00, bfr[nr][0], acc[0][nr]);
        acc[0][nr] = mfma16(a01, bfr[nr][1], acc[0][nr]);
        acc[1][nr] = mfma16(a10, bfr[nr][0], acc[1][nr]);
        acc[1][nr] = mfma16(a11, bfr[nr][1], acc[1][nr]);
      }
      __builtin_amdgcn_s_setprio(0);
      asm volatile("s_barrier" ::: "memory");
    }
    {
      bf16x8 a00 = ldfrag(Ab, wm * 64 + 2 * 16 + l15, 0);
      bf16x8 a01 = ldfrag(Ab, wm * 64 + 2 * 16 + l15, 1);
      bf16x8 a10 = ldfrag(Ab, wm * 64 + 3 * 16 + l15, 0);
      bf16x8 a11 = ldfrag(Ab, wm * 64 + 3 * 16 + l15, 1);
      if (stB) stageB(kt + 2, &Bs[kt & 1][0]);
      asm volatile("s_barrier" ::: "memory");
      asm volatile("s_waitcnt lgkmcnt(0)" ::: "memory");
      __builtin_amdgcn_sched_barrier(0);
      __builtin_amdgcn_s_setprio(1);
      #pragma unroll
      for (int nr = 0; nr < 4; ++nr) {
        acc[2][nr] = mfma16(a00, bfr[nr][0], acc[2][nr]);
        acc[2][nr] = mfma16(a01, bfr[nr][1], acc[2][nr]);
        acc[3][nr] = mfma16(a10, bfr[nr][0], acc[3][nr]);
        acc[3][nr] = mfma16(a11, bfr[nr][1], acc[3][nr]);
      }
      __builtin_amdgcn_s_setprio(0);
      if (stB) asm volatile("s_waitcnt vmcnt(4)" ::: "memory");
      else     asm volatile("s_waitcnt vmcnt(0)" ::: "memory");
      asm volatile("s_barrier" ::: "memory");
    }
  }

  #pragma unroll
  for (int mr = 0; mr < 4; ++mr)
    #pragma unroll
    for (int nr = 0; nr < 4; ++nr)
      #pragma unroll
      for (int i = 0; i < 4; ++i) {
        long r = m0 + wm * 64 + mr * 16 + l4 * 4 + i;
        long c = n0 + wn * 64 + nr * 16 + l15;
        if (OUT_BF16) ((bf16_t*)Cout)[r * N + c] = (bf16_t)acc[mr][nr][i];
        else          ((float*)Cout)[r * N + c] = acc[mr][nr][i];
      }
}

// ---------------- RoPE (rot_dim=32) + q-scale, in-place on qkv[4096][6144] ----------------
__global__ __launch_bounds__(256) void rope_scale(bf16_t* __restrict__ qkv) {
  int t = blockIdx.x * 256 + threadIdx.x;    // [0, 4096*256)
  int m = t >> 8;
  int h = (t >> 4) & 15;
  int j = t & 15;
  int n = m & 2047;
  const float L2_10000_D16 = 0.8304820237218406f;  // log2(10000)/16
  float inv = exp2f(-(float)j * L2_10000_D16);     // 10000^(-j/16)
  float ang = (float)n * inv;
  float s, c;
  sincosf(ang, &s, &c);
  const float scale = 0.08838834764831845f;        // 128^-0.5
  bf16_t* qp = qkv + (long)m * 6144 + h * 128;
  float a = (float)qp[j], b = (float)qp[j + 16];
  qp[j]      = (bf16_t)((a * c - b * s) * scale);
  qp[j + 16] = (bf16_t)((b * c + a * s) * scale);
  #pragma unroll
  for (int u = 0; u < 6; ++u) {
    int d = 32 + j + u * 16;
    qp[d] = (bf16_t)((float)qp[d] * scale);
  }
  bf16_t* kp = qp + 2048;
  a = (float)kp[j]; b = (float)kp[j + 16];
  kp[j]      = (bf16_t)(a * c - b * s);
  kp[j + 16] = (bf16_t)(b * c + a * s);
}

// ---------------- causal flash attention (swapped-QK^T, 8 waves, QBLK=16) ----------------
__global__ __launch_bounds__(512, 4) void attn_causal(const bf16_t* __restrict__ qkv,
                                                      bf16_t* __restrict__ ao) {
  const int id = blockIdx.x;
  const int qt = 15 - (id >> 5);             // LPT: longest first
  const int bh = id & 31;
  const int b = bh >> 4, h = bh & 15;
  const int t = threadIdx.x;
  const int wid = t >> 6, l = t & 63;
  const int l15 = l & 15, l4 = l >> 4;
  __shared__ __align__(16) bf16_t Ks0[64 * 128];
  __shared__ __align__(16) bf16_t Ks1[64 * 128];
  __shared__ __align__(16) bf16_t Vt[128 * 64];
  __shared__ __align__(16) bf16_t Pb[8][16 * 72];
  const bf16_t* base = qkv + (long)b * 2048 * 6144 + h * 128;
  const int q0w = qt * 128 + wid * 16;
  bf16x8 qf[4];
  #pragma unroll
  for (int ks = 0; ks < 4; ++ks)
    qf[ks] = *(const bf16x8*)(base + (long)(q0w + l15) * 6144 + ks * 32 + l4 * 8);
  f32x4 o[8] = {};
  float mrun = -1.0e30f, lrun = 0.f;
  bf16_t* pbuf = Pb[wid];
  bf16x8 vr0, vr1;
  const int ntiles = 2 * qt + 2;

  auto stageK = [&](int tile, bf16_t* dst) {
    const bf16_t* src = base + 2048 + (long)tile * 64 * 6144;
    #pragma unroll
    for (int it = 0; it < 2; ++it) {
      int s = it * 512 + t;
      int krow = s >> 4, kc = s & 15;
      int ksc = kc ^ (krow & 7);
      gload16(src + (long)krow * 6144 + ksc * 8, dst + (size_t)s * 8);
    }
  };
  auto loadV = [&](int tile) {
    const bf16_t* vsr = base + 4096 + (long)(tile * 64 + l) * 6144;
    vr0 = *(const bf16x8*)(vsr + wid * 8);
    vr1 = *(const bf16x8*)(vsr + (8 + wid) * 8);
  };
  auto writeVt = [&]() {
    #pragma unroll
    for (int it = 0; it < 2; ++it) {
      int c = it * 8 + wid;
      bf16x8 v = it ? vr1 : vr0;
      #pragma unroll
      for (int e = 0; e < 8; ++e) {
        int d = c * 8 + e;
        Vt[d * 64 + (((l >> 3) ^ e) * 8) + (l & 7)] = v[e];
      }
    }
  };
  auto compute = [&](int kv0, const bf16_t* ksb) {
    if (kv0 > q0w + 15) return;
    f32x4 sa[4] = {};
    __builtin_amdgcn_s_setprio(1);
    #pragma unroll
    for (int ks = 0; ks < 4; ++ks) {
      #pragma unroll
      for (int nb = 0; nb < 4; ++nb) {
        int row = nb * 16 + l15;
        int cs = (ks * 4 + l4) ^ (row & 7);
        bf16x8 kf = *(const bf16x8*)(ksb + row * 128 + cs * 8);
        sa[nb] = mfma16(kf, qf[ks], sa[nb]);   // S^T: row=kv, col=q
      }
    }
    __builtin_amdgcn_s_setprio(0);
    if (kv0 + 63 > q0w) {
      const int q = q0w + l15;
      #pragma unroll
      for (int nb = 0; nb < 4; ++nb)
        #pragma unroll
        for (int i = 0; i < 4; ++i)
          if (kv0 + nb * 16 + l4 * 4 + i > q) sa[nb][i] = -3.0e38f;
    }
    f32x4 mv;
    #pragma unroll
    for (int i = 0; i < 4; ++i)
      mv[i] = fmaxf(fmaxf(sa[0][i], sa[1][i]), fmaxf(sa[2][i], sa[3][i]));
    float pmax = fmaxf(fmaxf(mv[0], mv[1]), fmaxf(mv[2], mv[3]));
    pmax = fmaxf(pmax, __shfl_xor(pmax, 16));
    pmax = fmaxf(pmax, __shfl_xor(pmax, 32));
    if (!__all(pmax - mrun <= 8.0f)) {
      float mnew = fmaxf(mrun, pmax);
      float corr = __expf(mrun - mnew);
      mrun = mnew;
      lrun *= corr;
      float cc[4];
      #pragma unroll
      for (int i = 0; i < 4; ++i) cc[i] = __shfl(corr, l4 * 4 + i);
      #pragma unroll
      for (int nf = 0; nf < 8; ++nf)
        #pragma unroll
        for (int i = 0; i < 4; ++i) o[nf][i] *= cc[i];
    }
    float ps = 0.f;
    #pragma unroll
    for (int nb = 0; nb < 4; ++nb)
      #pragma unroll
      for (int i = 0; i < 4; ++i) {
        float p = __expf(sa[nb][i] - mrun);
        sa[nb][i] = p;
        ps += p;
      }
    ps += __shfl_xor(ps, 16);
    ps += __shfl_xor(ps, 32);
    lrun += ps;
    #pragma unroll
    for (int nb = 0; nb < 4; ++nb) {
      int cw = (nb * 2 + (l4 >> 1)) ^ (l15 & 7);
      uint32_t* dst = (uint32_t*)(pbuf + l15 * 72 + cw * 8 + (l4 & 1) * 4);
      dst[0] = pack2(sa[nb][0], sa[nb][1]);
      dst[1] = pack2(sa[nb][2], sa[nb][3]);
    }
    #pragma unroll
    for (int ks2 = 0; ks2 < 2; ++ks2) {
      bf16x8 pf = *(const bf16x8*)(pbuf + l15 * 72 + (((ks2 * 4 + l4) ^ (l15 & 7)) * 8));
      __builtin_amdgcn_s_setprio(1);
      #pragma unroll
      for (int nf = 0; nf < 8; ++nf) {
        int row = nf * 16 + l15;
        bf16x8 vf = *(const bf16x8*)(Vt + row * 64 + (((ks2 * 4 + l4) ^ (row & 7)) * 8));
        o[nf] = mfma16(pf, vf, o[nf]);
      }
      __builtin_amdgcn_s_setprio(0);
    }
  };

  stageK(0, Ks0);
  loadV(0);
  writeVt();
  __syncthreads();
  for (int tile = 0; tile < ntiles; ++tile) {
    bf16_t* cur = (tile & 1) ? Ks1 : Ks0;
    bf16_t* nxt = (tile & 1) ? Ks0 : Ks1;
    const bool pre = (tile + 1 < ntiles);
    if (pre) { stageK(tile + 1, nxt); loadV(tile + 1); }
    compute(tile * 64, cur);
    __syncthreads();
    if (pre) writeVt();
    __syncthreads();
  }
  float linv = 1.f / lrun;
  float li[4];
  #pragma unroll
  for (int i = 0; i < 4; ++i) li[i] = __shfl(linv, l4 * 4 + i);
  bf16_t* aob = ao + (long)b * 2048 * 2048 + h * 128;
  #pragma unroll
  for (int i = 0; i < 4; ++i) {
    long qrow = q0w + l4 * 4 + i;
    #pragma unroll
    for (int nf = 0; nf < 8; ++nf)
      aob[qrow * 2048 + nf * 16 + l15] = (bf16_t)(o[nf][i] * li[i]);
  }
}

// ---------------- launch ----------------
extern "C" void kernel_launch(void* const* d_in, const int* in_sizes, int n_in,
                              void* d_out, int out_size, void* d_ws, size_t ws_size,
                              hipStream_t stream) {
  const float* x     = (const float*)d_in[0];
  const float* w_qkv = (const float*)d_in[1];
  const float* w_out = (const float*)d_in[2];
  char* ws = (char*)d_ws;
  bf16_t* xb    = (bf16_t*)(ws + 0L);           // 16 MiB  (4096x2048)
  bf16_t* wqkvb = (bf16_t*)(ws + 16777216L);    // 24 MiB  (6144x2048)
  bf16_t* woutb = (bf16_t*)(ws + 41943040L);    //  8 MiB  (2048x2048)
  bf16_t* qkv   = (bf16_t*)(ws + 50331648L);    // 48 MiB  (4096x6144)
  bf16_t* ao    = (bf16_t*)(ws + 100663296L);   // 16 MiB  (4096x2048) -> end 112 MiB

  cast_f32_to_bf16<<<2048, 256, 0, stream>>>(x, xb, 1048576);
  cast_f32_to_bf16<<<2048, 256, 0, stream>>>(w_qkv, wqkvb, 1572864);
  cast_f32_to_bf16<<<1024, 256, 0, stream>>>(w_out, woutb, 524288);
  // qkv[m][f] = sum_c x[m][c] * w_qkv[f][c]  — 256x384, 256 blocks = 1 exact round
  gemm_qkv<<<dim3(16, 16), 512, 0, stream>>>(xb, wqkvb, qkv, 4096, 6144, 2048);
  rope_scale<<<4096, 256, 0, stream>>>(qkv);
  attn_causal<<<512, 512, 0, stream>>>(qkv, ao);
  // out[m][c] = sum_f ao[m][f] * w_out[c][f]  — 128x256, 256 blocks = 1 round
  gemm8p_bt<false><<<dim3(32, 8), 512, 0, stream>>>(ao, woutb, d_out, 4096, 2048, 2048);
}